// Round 12
// baseline (861.378 us; speedup 1.0000x reference)
//
#include <hip/hip_runtime.h>
#include <stdint.h>

#define NCLS 80
#define CELLS 8400      // 6400 + 1600 + 400
#define PRE 1000
#define KEEP 100
#define CAP 4096        // fallback candidate cap
#define NBINS 16384     // fallback histogram bins
#define NIMG 32
#define SUBS 8
#define SUBCAP 2048     // per-sub store cap (total 16384/image)
#define GBINS 4096      // gather-phase LDS histogram bins
#define COMPCAP 2048
#define T0 0.75f        // static pre-store threshold (top-1000 cutoff ~0.82 for N(0,1))
#define SCREEN 1.0886f  // logit(0.75)=1.0986 minus slack; exact test done on sigm product

__device__ __forceinline__ float sigm(float x) { return 1.0f / (1.0f + __expf(-x)); }

__device__ __forceinline__ void lvlinfo(int cell, int& li, int& loc, int& HW) {
  if (cell < 6400)      { li = 0; loc = cell;        HW = 6400; }
  else if (cell < 8000) { li = 1; loc = cell - 6400; HW = 1600; }
  else                  { li = 2; loc = cell - 8000; HW = 400;  }
}

// ---------------- K1: pure single-stream sweep ----------------
// Grid (493, NIMG): block owns 1024 contiguous float4s (16KB) of one level's cls.
// 4 forced-batch loads/thread (max-tree consumes all -> all 4 issue before use).
// NOTHING else in the hot path: decode divisions, obj scalar load (L2-hot) and
// sigmoids only inside the 13.8%-rate element branch. Copy-ubench shape, no
// second stream.
__global__ __launch_bounds__(256) void k_pass1(
    const float* __restrict__ cls0, const float* __restrict__ cls1, const float* __restrict__ cls2,
    const float* __restrict__ obj0, const float* __restrict__ obj1, const float* __restrict__ obj2,
    uint32_t* __restrict__ cnt75, uint64_t* __restrict__ cand75) {
  const int b = blockIdx.y;
  const int bx = blockIdx.x;
  int lvl, lb_f4, nf4, HW, cellbase;
  const float* clsB; const float* objB;
  if (bx < 375)      { lvl = 0; lb_f4 = bx * 1024;         nf4 = 384000; HW = 6400; cellbase = 0;    clsB = cls0; objB = obj0; }
  else if (bx < 469) { lvl = 1; lb_f4 = (bx - 375) * 1024; nf4 = 96000;  HW = 1600; cellbase = 6400; clsB = cls1; objB = obj1; }
  else               { lvl = 2; lb_f4 = (bx - 469) * 1024; nf4 = 24000;  HW = 400;  cellbase = 8000; clsB = cls2; objB = obj2; }
  const float4* cb4 = (const float4*)(clsB + (size_t)b * 240 * HW);
  const float* objb = objB + (size_t)b * 3 * HW;
  const int sub = bx & (SUBS - 1);
  const int j0 = lb_f4 + threadIdx.x;
  const int j1 = j0 + 256, j2 = j0 + 512, j3 = j0 + 768;

  float4 v0 = cb4[j0];                       // slot 0 always valid (block base aligned)
  float4 v1 = cb4[j1 < nf4 ? j1 : j0];
  float4 v2 = cb4[j2 < nf4 ? j2 : j0];
  float4 v3 = cb4[j3 < nf4 ? j3 : j0];
  float m0 = fmaxf(fmaxf(v0.x, v0.y), fmaxf(v0.z, v0.w));
  float m1 = fmaxf(fmaxf(v1.x, v1.y), fmaxf(v1.z, v1.w));
  float m2 = fmaxf(fmaxf(v2.x, v2.y), fmaxf(v2.z, v2.w));
  float m3 = fmaxf(fmaxf(v3.x, v3.y), fmaxf(v3.z, v3.w));
  if (fmaxf(fmaxf(m0, m1), fmaxf(m2, m3)) <= SCREEN) return;   // forces all 4 in flight

  auto proc = [&](float4 v, float mv, int j) {
    if (mv <= SCREEN) return;
    int ch, w4;
    if (lvl == 0)      { ch = j / 1600; w4 = j - ch * 1600; }
    else if (lvl == 1) { ch = j / 400;  w4 = j - ch * 400; }
    else               { ch = j / 100;  w4 = j - ch * 100; }
    const int p = ch / 80;
    const int c = ch - p * 80;
    float vv[4] = { v.x, v.y, v.z, v.w };
#pragma unroll
    for (int k = 0; k < 4; ++k) {
      if (vv[k] > SCREEN) {                        // conservative logit screen
        float ov = objb[p * HW + w4 * 4 + k];      // L2-hot scalar (rare path)
        float s = sigm(vv[k]) * sigm(ov);          // exact arithmetic (same as ref)
        if (s > T0) {
          uint32_t slot = atomicAdd(&cnt75[b * SUBS + sub], 1u);
          if (slot < SUBCAP) {
            uint32_t flat = (uint32_t)(((cellbase + w4 * 4 + k) * 3 + p) * 80 + c);
            cand75[((size_t)(b * SUBS + sub)) * SUBCAP + slot] =
                ((uint64_t)__float_as_uint(s) << 32) | (uint64_t)(0xFFFFFFFFu - flat);
          }
        }
      }
    }
  };
  proc(v0, m0, j0);
  if (j1 < nf4) proc(v1, m1, j1);
  if (j2 < nf4) proc(v2, m2, j2);
  if (j3 < nf4) proc(v3, m3, j3);
}

// ---------------- K3: per-image gather + exact top-1000 + decode ----------------
// Bad path now also zeroes this image's fallback-hist slice (replaces k_zero_hist).
__global__ __launch_bounds__(1024) void k_gather(
    const uint64_t* __restrict__ cand75, const uint32_t* __restrict__ cnt75,
    uint32_t* __restrict__ flags, uint32_t* __restrict__ histg,
    const float* __restrict__ bbox0, const float* __restrict__ bbox1, const float* __restrict__ bbox2,
    const float* __restrict__ priors, const float* __restrict__ strides,
    float* __restrict__ topS, int* __restrict__ topLab, float* __restrict__ topBox,
    uint32_t* __restrict__ nvArr) {
  __shared__ uint32_t hist[GBINS];
  __shared__ uint64_t comp[COMPCAP];
  __shared__ uint32_t seg[64];
  __shared__ uint32_t ncomp_s, cb_s;
  const int b = blockIdx.x;
  const int tid = threadIdx.x;
  uint32_t tot = 0; bool bad = false;
  for (int s = 0; s < SUBS; ++s) {
    uint32_t cc = cnt75[b * SUBS + s];
    tot += cc;
    if (cc > SUBCAP) bad = true;
  }
  if (tot < (uint32_t)PRE) bad = true;
  if (bad) {
    if (tid == 0) flags[b] = 1u;
    for (int i = tid; i < NBINS; i += 1024) histg[(size_t)b * NBINS + i] = 0;
    return;
  }

  for (int i = tid; i < GBINS; i += 1024) hist[i] = 0;
  if (tid == 0) ncomp_s = 0;
  __syncthreads();
  for (int s = 0; s < SUBS; ++s) {
    uint32_t c = cnt75[b * SUBS + s];
    const uint64_t* src = cand75 + ((size_t)(b * SUBS + s)) * SUBCAP;
    for (int i = tid; i < (int)c; i += 1024) {
      uint32_t hi = (uint32_t)(src[i] >> 32);
      uint32_t bin = (hi - 0x3F400000u) >> 10;
      if (bin > GBINS - 1) bin = GBINS - 1;
      atomicAdd(&hist[bin], 1u);
    }
  }
  __syncthreads();
  if (tid < 64) {
    uint32_t s = 0;
    for (int k = 0; k < 64; ++k) s += hist[tid * 64 + k];
    seg[tid] = s;
  }
  __syncthreads();
  if (tid == 0) {
    uint32_t acc = 0; int segi = 0;
    for (int i = 63; i >= 0; --i) {
      if (acc + seg[i] >= (uint32_t)PRE) { segi = i; break; }
      acc += seg[i];
    }
    uint32_t cb = 0;
    for (int k = 63; k >= 0; --k) {
      acc += hist[segi * 64 + k];
      if (acc >= (uint32_t)PRE) { cb = (uint32_t)(segi * 64 + k); break; }
    }
    cb_s = cb;
  }
  __syncthreads();
  const uint32_t cb = cb_s;
  for (int s = 0; s < SUBS; ++s) {
    uint32_t c = cnt75[b * SUBS + s];
    const uint64_t* src = cand75 + ((size_t)(b * SUBS + s)) * SUBCAP;
    for (int i = tid; i < (int)c; i += 1024) {
      uint64_t key = src[i];
      uint32_t hi = (uint32_t)(key >> 32);
      uint32_t bin = (hi - 0x3F400000u) >> 10;
      if (bin > GBINS - 1) bin = GBINS - 1;
      if (bin >= cb) {
        uint32_t pos = atomicAdd(&ncomp_s, 1u);
        if (pos < COMPCAP) comp[pos] = key;
      }
    }
  }
  __syncthreads();
  const uint32_t ncomp = ncomp_s;
  if (ncomp > COMPCAP) {
    if (tid == 0) flags[b] = 1u;
    for (int i = tid; i < NBINS; i += 1024) histg[(size_t)b * NBINS + i] = 0;
    return;
  }
  const int N = (ncomp <= 1024u) ? 1024 : COMPCAP;   // adaptive sort size
  for (int i = tid; i < N; i += 1024) if (i >= (int)ncomp) comp[i] = 0ull;
  __syncthreads();
  for (int k = 2; k <= N; k <<= 1) {
    for (int j = k >> 1; j > 0; j >>= 1) {
      for (int i = tid; i < N; i += 1024) {
        int p = i ^ j;
        if (p > i) {
          uint64_t a = comp[i], c = comp[p];
          bool asc = (i & k) != 0;
          if (asc ? (a > c) : (a < c)) { comp[i] = c; comp[p] = a; }
        }
      }
      __syncthreads();
    }
  }
  if (tid == 0) nvArr[b] = (uint32_t)PRE;
  for (int t = tid; t < PRE; t += 1024) {
    uint64_t key = comp[t];
    float sc = __uint_as_float((uint32_t)(key >> 32));
    uint32_t flat = 0xFFFFFFFFu - (uint32_t)(key & 0xFFFFFFFFull);
    uint32_t n = flat / 80u; int lab = (int)(flat - n * 80u);
    uint32_t g = n / 3u; uint32_t p = n - g * 3u;
    int li, loc, HW; lvlinfo((int)g, li, loc, HW);
    const float* bb = li == 0 ? bbox0 : (li == 1 ? bbox1 : bbox2);
    size_t o = ((size_t)b * 12 + p * 4) * HW + loc;
    float p0 = sigm(bb[o]);
    float p1 = sigm(bb[o + (size_t)HW]);
    float p2 = sigm(bb[o + 2 * (size_t)HW]);
    float p3 = sigm(bb[o + 3 * (size_t)HW]);
    float4 pr = *(const float4*)(priors + (size_t)n * 4);
    float st = strides[n];
    float cx = (pr.x + pr.z) * 0.5f, cy = (pr.y + pr.w) * 0.5f;
    float w = pr.z - pr.x, hh = pr.w - pr.y;
    float xc = (p0 - 0.5f) * 2.0f * st + cx;
    float yc = (p1 - 0.5f) * 2.0f * st + cy;
    float wp = p2 * 2.0f; wp = wp * wp * w;
    float hp = p3 * 2.0f; hp = hp * hp * hh;
    topS[(size_t)b * PRE + t] = sc;
    topLab[(size_t)b * PRE + t] = lab;
    *(float4*)(topBox + ((size_t)b * PRE + t) * 4) =
        make_float4(xc - wp * 0.5f, yc - hp * 0.5f, xc + wp * 0.5f, yc + hp * 0.5f);
  }
}

// ================= FALLBACK PATH (per-image flag; never runs for typical data) ============
// hist + (fused) cutoff via per-image done-counter: last of 9 blocks computes cutoff.
__global__ __launch_bounds__(256) void k_hist_fb(
    const float* __restrict__ cls0, const float* __restrict__ cls1, const float* __restrict__ cls2,
    const float* __restrict__ obj0, const float* __restrict__ obj1, const float* __restrict__ obj2,
    uint32_t* __restrict__ hist, const uint32_t* __restrict__ flags,
    uint32_t* __restrict__ histDone, uint32_t* __restrict__ cutoff) {
  const int b = blockIdx.y;
  if (flags[b] == 0u) return;
  __shared__ uint32_t h[NBINS];
  __shared__ uint32_t seg[256];
  __shared__ uint32_t lastArrive;
  for (int i = threadIdx.x; i < NBINS; i += 256) h[i] = 0;
  __syncthreads();
  const int c0 = (blockIdx.x * 256 + threadIdx.x) * 4;
  if (c0 < CELLS) {
    int li, loc, HW; lvlinfo(c0, li, loc, HW);
    const float* cls = li == 0 ? cls0 : (li == 1 ? cls1 : cls2);
    const float* obj = li == 0 ? obj0 : (li == 1 ? obj1 : obj2);
    float os[3][4];
#pragma unroll
    for (int p = 0; p < 3; ++p) {
      float4 o = *(const float4*)(obj + ((size_t)b * 3 + p) * HW + loc);
      os[p][0] = sigm(o.x); os[p][1] = sigm(o.y); os[p][2] = sigm(o.z); os[p][3] = sigm(o.w);
    }
    for (int p = 0; p < 3; ++p) {
      const float* cp = cls + ((size_t)b * 240 + p * 80) * HW + loc;
      for (int c = 0; c < 80; ++c) {
        float4 v = *(const float4*)(cp + (size_t)c * HW);
        float sv[4] = { sigm(v.x) * os[p][0], sigm(v.y) * os[p][1],
                        sigm(v.z) * os[p][2], sigm(v.w) * os[p][3] };
#pragma unroll
        for (int k = 0; k < 4; ++k) {
          if (sv[k] > 0.25f) {
            uint32_t key = (__float_as_uint(sv[k]) - 0x3E800000u) >> 10;
            if (key > NBINS - 1) key = NBINS - 1;
            atomicAdd(&h[key], 1u);
          }
        }
      }
    }
  }
  __syncthreads();
  for (int i = threadIdx.x; i < NBINS; i += 256) {
    uint32_t v = h[i];
    if (v) atomicAdd(&hist[(size_t)b * NBINS + i], v);
  }
  __syncthreads();          // all this block's global atomics drained before barrier
  __threadfence();
  if (threadIdx.x == 0) lastArrive = atomicAdd(&histDone[b], 1u);
  __syncthreads();
  if (lastArrive != 8) return;     // not the last of 9 blocks
  __threadfence();
  // ---- fused cutoff (256 threads), atomic reads for device-coherent hist view ----
  uint32_t* hb = hist + (size_t)b * NBINS;
  uint32_t s = 0;
  for (int k = 0; k < 64; ++k) s += atomicOr(&hb[threadIdx.x * 64 + k], 0u);
  seg[threadIdx.x] = s;
  __syncthreads();
  if (threadIdx.x == 0) {
    uint32_t acc = 0; int segi = -1;
    for (int i = 255; i >= 0; --i) {
      if (acc + seg[i] >= (uint32_t)PRE) { segi = i; break; }
      acc += seg[i];
    }
    uint32_t cut = 0;
    if (segi >= 0) {
      for (int k = 63; k >= 0; --k) {
        acc += atomicOr(&hb[segi * 64 + k], 0u);
        if (acc >= (uint32_t)PRE) { cut = (uint32_t)(segi * 64 + k); break; }
      }
    }
    cutoff[b] = cut;
  }
}

// collect + (fused) sort/decode via per-image done-counter: last of 9 blocks sorts.
__global__ __launch_bounds__(256) void k_collect_fb(
    const float* __restrict__ cls0, const float* __restrict__ cls1, const float* __restrict__ cls2,
    const float* __restrict__ obj0, const float* __restrict__ obj1, const float* __restrict__ obj2,
    const uint32_t* __restrict__ cutoff, uint32_t* __restrict__ candCount,
    uint64_t* __restrict__ cand, const uint32_t* __restrict__ flags,
    uint32_t* __restrict__ collectDone,
    const float* __restrict__ bbox0, const float* __restrict__ bbox1, const float* __restrict__ bbox2,
    const float* __restrict__ priors, const float* __restrict__ strides,
    float* __restrict__ topS, int* __restrict__ topLab, float* __restrict__ topBox,
    uint32_t* __restrict__ nvArr) {
  const int b = blockIdx.y;
  if (flags[b] == 0u) return;
  __shared__ uint64_t s[CAP];          // 32 KB (fallback-only; occupancy irrelevant)
  __shared__ uint32_t lastArrive;
  const uint32_t cut = cutoff[b];
  const int c0 = (blockIdx.x * 256 + threadIdx.x) * 4;
  if (c0 < CELLS) {
    int li, loc, HW; lvlinfo(c0, li, loc, HW);
    const float* cls = li == 0 ? cls0 : (li == 1 ? cls1 : cls2);
    const float* obj = li == 0 ? obj0 : (li == 1 ? obj1 : obj2);
    float os[3][4];
#pragma unroll
    for (int p = 0; p < 3; ++p) {
      float4 o = *(const float4*)(obj + ((size_t)b * 3 + p) * HW + loc);
      os[p][0] = sigm(o.x); os[p][1] = sigm(o.y); os[p][2] = sigm(o.z); os[p][3] = sigm(o.w);
    }
    for (int p = 0; p < 3; ++p) {
      const float* cp = cls + ((size_t)b * 240 + p * 80) * HW + loc;
      for (int c = 0; c < 80; ++c) {
        float4 v = *(const float4*)(cp + (size_t)c * HW);
        float sv[4] = { sigm(v.x) * os[p][0], sigm(v.y) * os[p][1],
                        sigm(v.z) * os[p][2], sigm(v.w) * os[p][3] };
#pragma unroll
        for (int k = 0; k < 4; ++k) {
          float sk = sv[k];
          if (sk > 0.25f) {
            uint32_t key = (__float_as_uint(sk) - 0x3E800000u) >> 10;
            if (key >= cut) {
              uint32_t pos = atomicAdd(&candCount[b], 1u);
              if (pos < CAP) {
                uint32_t flat = (uint32_t)((((c0 + k) * 3 + p) * 80) + c);
                cand[(size_t)b * CAP + pos] =
                    ((uint64_t)__float_as_uint(sk) << 32) | (uint64_t)(0xFFFFFFFFu - flat);
              }
            }
          }
        }
      }
    }
  }
  __syncthreads();
  __threadfence();                      // make stores device-visible before arrival
  if (threadIdx.x == 0) lastArrive = atomicAdd(&collectDone[b], 1u);
  __syncthreads();
  if (lastArrive != 8) return;          // not last of 9
  __threadfence();
  // ---- fused sort (256 threads, 16 elems/thread) + decode ----
  uint32_t cnt = atomicOr(&candCount[b], 0u); if (cnt > (uint32_t)CAP) cnt = CAP;
  for (int i = threadIdx.x; i < CAP; i += 256)
    s[i] = (i < (int)cnt) ? cand[(size_t)b * CAP + i] : 0ull;
  __syncthreads();
  for (int k = 2; k <= CAP; k <<= 1) {
    for (int j = k >> 1; j > 0; j >>= 1) {
      for (int i = threadIdx.x; i < CAP; i += 256) {
        int p = i ^ j;
        if (p > i) {
          uint64_t a = s[i], c = s[p];
          bool asc = (i & k) != 0;
          if (asc ? (a > c) : (a < c)) { s[i] = c; s[p] = a; }
        }
      }
      __syncthreads();
    }
  }
  const int NV = (int)(cnt < (uint32_t)PRE ? cnt : (uint32_t)PRE);
  if (threadIdx.x == 0) nvArr[b] = (uint32_t)NV;
  for (int t = threadIdx.x; t < PRE; t += 256) {
    float sc = 0.0f; int lab = 0; float b0 = 0, b1 = 0, b2v = 0, b3 = 0;
    if (t < NV) {
      uint64_t key = s[t];
      sc = __uint_as_float((uint32_t)(key >> 32));
      uint32_t flat = 0xFFFFFFFFu - (uint32_t)(key & 0xFFFFFFFFull);
      uint32_t n = flat / 80u; lab = (int)(flat - n * 80u);
      uint32_t g = n / 3u; uint32_t p = n - g * 3u;
      int li, loc, HW; lvlinfo((int)g, li, loc, HW);
      const float* bb = li == 0 ? bbox0 : (li == 1 ? bbox1 : bbox2);
      size_t o = ((size_t)b * 12 + p * 4) * HW + loc;
      float p0 = sigm(bb[o]);
      float p1 = sigm(bb[o + (size_t)HW]);
      float p2 = sigm(bb[o + 2 * (size_t)HW]);
      float p3 = sigm(bb[o + 3 * (size_t)HW]);
      float4 pr = *(const float4*)(priors + (size_t)n * 4);
      float st = strides[n];
      float cx = (pr.x + pr.z) * 0.5f, cy = (pr.y + pr.w) * 0.5f;
      float w = pr.z - pr.x, hh = pr.w - pr.y;
      float xc = (p0 - 0.5f) * 2.0f * st + cx;
      float yc = (p1 - 0.5f) * 2.0f * st + cy;
      float wp = p2 * 2.0f; wp = wp * wp * w;
      float hp = p3 * 2.0f; hp = hp * hp * hh;
      b0 = xc - wp * 0.5f; b1 = yc - hp * 0.5f; b2v = xc + wp * 0.5f; b3 = yc + hp * 0.5f;
    }
    topS[(size_t)b * PRE + t] = sc;
    topLab[(size_t)b * PRE + t] = lab;
    *(float4*)(topBox + ((size_t)b * PRE + t) * 4) = make_float4(b0, b1, b2v, b3);
  }
}

// ---------------- K5: IoU suppression bitmask (63 blocks/image) ----------------
__global__ __launch_bounds__(256) void k_iou(
    const float* __restrict__ topBox, const int* __restrict__ topLab,
    const uint32_t* __restrict__ nvArr, uint64_t* __restrict__ mask) {
  __shared__ float4 bx[PRE];
  __shared__ int lb[PRE];
  const int b = blockIdx.y;
  const int NV = (int)nvArr[b];
  for (int i = threadIdx.x; i < PRE; i += 256) {
    bx[i] = *(const float4*)(topBox + ((size_t)b * PRE + i) * 4);
    lb[i] = topLab[(size_t)b * PRE + i];
  }
  __syncthreads();
  for (int task = blockIdx.x * 256 + threadIdx.x; task < PRE * 16; task += gridDim.x * 256) {
    const int i = task >> 4, w = task & 15;
    uint64_t m = 0;
    if (i < NV) {
      const float4 a = bx[i]; const int la = lb[i];
      const float areaA = (a.z - a.x) * (a.w - a.y);
      const int j0 = w << 6;
      const int jend = (j0 + 64 < NV) ? j0 + 64 : NV;
      for (int j = (j0 > i + 1 ? j0 : i + 1); j < jend; ++j) {
        if (lb[j] != la) continue;
        const float4 c = bx[j];
        float xx1 = fmaxf(a.x, c.x), yy1 = fmaxf(a.y, c.y);
        float xx2 = fminf(a.z, c.z), yy2 = fminf(a.w, c.w);
        float iw = fmaxf(xx2 - xx1, 0.0f), ih = fmaxf(yy2 - yy1, 0.0f);
        float inter = iw * ih;
        float areaB = (c.z - c.x) * (c.w - c.y);
        float iou = inter / (areaA + areaB - inter + 1e-7f);
        if (iou > 0.65f) m |= (1ull << (j - j0));
      }
    }
    mask[((size_t)b * PRE + i) * 16 + w] = m;
  }
}

// ---------------- K6: serial greedy scan (branchless, pipelined) + output assembly --------
__global__ __launch_bounds__(256) void k_scan_out(
    const uint64_t* __restrict__ mask, const float* __restrict__ topS,
    const int* __restrict__ topLab, const float* __restrict__ topBox,
    const uint32_t* __restrict__ nvArr, float* __restrict__ out) {
  __shared__ uint64_t rows[PRE * 16];   // 125 KB
  __shared__ uint64_t keepw[16];
  __shared__ uint32_t pref[17];
  const int b = blockIdx.x;
  const int NV = (int)nvArr[b];
  for (int i = threadIdx.x; i < NV * 16; i += 256) rows[i] = mask[(size_t)b * PRE * 16 + i];
  __syncthreads();
  if (threadIdx.x < 64) {
    const int lane = threadIdx.x;
    uint64_t remv = 0, kw = 0;
    for (int w0 = 0; w0 * 64 < NV; ++w0) {
      uint64_t cur = (uint64_t)__shfl((unsigned long long)remv, w0);
      const int ie = (w0 * 64 + 64 < NV) ? w0 * 64 + 64 : NV;
      for (int i = w0 * 64; i < ie; ++i) {
        const int bi = i & 63;
        uint64_t rl = rows[i * 16 + (lane & 15)];
        uint64_t cw = rows[i * 16 + w0];
        const uint64_t keepm = ((cur >> bi) & 1ull) ? 0ull : ~0ull;
        cur |= cw & keepm;
        remv |= rl & keepm;
        kw |= (lane == w0) ? ((1ull << bi) & keepm) : 0ull;
      }
    }
    if (lane < 16) keepw[lane] = kw;
  }
  __syncthreads();
  if (threadIdx.x == 0) {
    uint32_t a = 0;
    for (int w = 0; w < 16; ++w) { pref[w] = a; a += (uint32_t)__popcll((unsigned long long)keepw[w]); }
    pref[16] = a;
  }
  __syncthreads();
  const uint32_t total = pref[16];
  const uint32_t num = total < (uint32_t)KEEP ? total : (uint32_t)KEEP;
  float* o_num = out;
  float* o_box = out + NIMG;
  float* o_s   = out + NIMG + NIMG * KEEP * 4;
  float* o_l   = o_s + NIMG * KEEP;
  if (threadIdx.x == 0) o_num[b] = (float)num;
  const int zstart = NV < KEEP ? NV : KEEP;
  for (int sidx = zstart + threadIdx.x; sidx < KEEP; sidx += 256) {
    ((float4*)o_box)[b * KEEP + sidx] = make_float4(0, 0, 0, 0);
    o_s[b * KEEP + sidx] = 0.0f;
    o_l[b * KEEP + sidx] = 0.0f;
  }
  for (int j = threadIdx.x; j < NV; j += 256) {
    const int wi = j >> 6, bi = j & 63;
    const uint64_t kword = keepw[wi];
    const int isk = (int)((kword >> bi) & 1ull);
    const uint32_t below = pref[wi] + (uint32_t)__popcll((unsigned long long)(kword & ((1ull << bi) - 1ull)));
    const uint32_t slot = isk ? below : (total + (uint32_t)j - below);
    if (slot < (uint32_t)KEEP) {
      ((float4*)o_box)[b * KEEP + slot] = *(const float4*)(topBox + ((size_t)b * PRE + j) * 4);
      o_s[b * KEEP + slot] = isk ? topS[(size_t)b * PRE + j] : 0.0f;
      o_l[b * KEEP + slot] = (float)topLab[(size_t)b * PRE + j];
    }
  }
}

extern "C" void kernel_launch(void* const* d_in, const int* in_sizes, int n_in,
                              void* d_out, int out_size, void* d_ws, size_t ws_size,
                              hipStream_t stream) {
  (void)in_sizes; (void)n_in; (void)out_size; (void)ws_size;
  const float* cls0 = (const float*)d_in[0];
  const float* cls1 = (const float*)d_in[1];
  const float* cls2 = (const float*)d_in[2];
  const float* bbox0 = (const float*)d_in[3];
  const float* bbox1 = (const float*)d_in[4];
  const float* bbox2 = (const float*)d_in[5];
  const float* obj0 = (const float*)d_in[6];
  const float* obj1 = (const float*)d_in[7];
  const float* obj2 = (const float*)d_in[8];
  const float* priors = (const float*)d_in[9];
  const float* strides = (const float*)d_in[10];
  float* out = (float*)d_out;

  char* ws = (char*)d_ws;
  size_t off = 0;
  auto alloc = [&](size_t bytes) -> void* {
    void* p = ws + off;
    off = (off + bytes + 255) & ~(size_t)255;
    return p;
  };
  // small scratch packed for a single memset
  uint32_t* small       = (uint32_t*)alloc(4096);
  uint32_t* flags       = small;                 // [32]
  uint32_t* cnt75       = small + 32;            // [256]
  uint32_t* candCount   = small + 288;           // [32]
  uint32_t* cutoff      = small + 320;           // [32]
  uint32_t* nvArr       = small + 352;           // [32]
  uint32_t* histDone    = small + 384;           // [32]
  uint32_t* collectDone = small + 416;           // [32]
  uint64_t* cand75    = (uint64_t*)alloc((size_t)NIMG * SUBS * SUBCAP * 8); // 4 MB
  uint32_t* hist      = (uint32_t*)alloc((size_t)NIMG * NBINS * 4);         // 2 MB (fb)
  uint64_t* cand      = (uint64_t*)alloc((size_t)NIMG * CAP * 8);           // 1 MB (fb)
  float*    topS      = (float*)alloc((size_t)NIMG * PRE * 4);
  int*      topLab    = (int*)alloc((size_t)NIMG * PRE * 4);
  float*    topBox    = (float*)alloc((size_t)NIMG * PRE * 16);
  uint64_t* maskbuf   = (uint64_t*)alloc((size_t)NIMG * PRE * 16 * 8);      // 4 MB

  hipMemsetAsync(small, 0, 4096, stream);

  k_pass1<<<dim3(493, NIMG), 256, 0, stream>>>(cls0, cls1, cls2, obj0, obj1, obj2,
                                               cnt75, cand75);
  k_gather<<<NIMG, 1024, 0, stream>>>(cand75, cnt75, flags, hist, bbox0, bbox1, bbox2,
                                      priors, strides, topS, topLab, topBox, nvArr);
  dim3 gScan(9, NIMG);
  k_hist_fb<<<gScan, 256, 0, stream>>>(cls0, cls1, cls2, obj0, obj1, obj2, hist, flags,
                                       histDone, cutoff);
  k_collect_fb<<<gScan, 256, 0, stream>>>(cls0, cls1, cls2, obj0, obj1, obj2,
                                          cutoff, candCount, cand, flags, collectDone,
                                          bbox0, bbox1, bbox2, priors, strides,
                                          topS, topLab, topBox, nvArr);
  k_iou<<<dim3(63, NIMG), 256, 0, stream>>>(topBox, topLab, nvArr, maskbuf);
  k_scan_out<<<NIMG, 256, 0, stream>>>(maskbuf, topS, topLab, topBox, nvArr, out);
}

// Round 13
// 623.470 us; speedup vs baseline: 1.3816x; 1.3816x over previous
//
#include <hip/hip_runtime.h>
#include <stdint.h>

#define NCLS 80
#define CELLS 8400      // 6400 + 1600 + 400
#define PRE 1000
#define KEEP 100
#define CAP 4096        // fallback candidate cap
#define NBINS 16384     // fallback histogram bins
#define NIMG 32
#define SUBS 8
#define SUBCAP 2048     // per-sub store cap (total 16384/image)
#define GBINS 4096      // gather-phase LDS histogram bins
#define COMPCAP 2048
#define T0 0.75f        // static pre-store threshold (top-1000 cutoff ~0.82 for N(0,1))
#define SCREEN 1.0886f  // logit(0.75)=1.0986 minus slack; exact test done on full float
#define HI16_SCREEN 0x3F8A  // (int16)hi16 > 0x3F8A  <=  v > 1.08496 (superset of SCREEN)

__device__ __forceinline__ float sigm(float x) { return 1.0f / (1.0f + __expf(-x)); }

__device__ __forceinline__ void lvlinfo(int cell, int& li, int& loc, int& HW) {
  if (cell < 6400)      { li = 0; loc = cell;        HW = 6400; }
  else if (cell < 8000) { li = 1; loc = cell - 6400; HW = 1600; }
  else                  { li = 2; loc = cell - 8000; HW = 400;  }
}

// ---------------- K1: hi16-screen sweep (half the delivered bytes) ----------------
// Thread owns one float column (spatial pos f0) and 40 channels (class half h, prior p).
// Hot loop: 8-wide batches of global_load_ushort (HIGH half of each float, stride 4B).
// Screen: (int16)hi > 0x3F8A (conservative superset of v>SCREEN; negatives fail).
// Survivors (~3.45%) reload the exact float + obj scalar and run the exact test.
__global__ __launch_bounds__(256) void k_pass1(
    const float* __restrict__ cls0, const float* __restrict__ cls1, const float* __restrict__ cls2,
    const float* __restrict__ obj0, const float* __restrict__ obj1, const float* __restrict__ obj2,
    uint32_t* __restrict__ cnt75, uint64_t* __restrict__ cand75) {
  const int b = blockIdx.y;
  const int bx = blockIdx.x;
  int w, r, HW, cellbase;
  const float* cls; const float* obj;
  if (bx < 150)      { w = bx / 6;        r = bx - w * 6;          HW = 6400; cellbase = 0;    cls = cls0; obj = obj0; }
  else if (bx < 192) { int q = bx - 150; w = q / 6; r = q - w * 6; HW = 1600; cellbase = 6400; cls = cls1; obj = obj1; }
  else               { int q = bx - 192; w = q / 6; r = q - w * 6; HW = 400;  cellbase = 8000; cls = cls2; obj = obj2; }
  const int h = r & 1;                  // class half: [h*40, h*40+40)
  const int p = r >> 1;                 // prior 0..2
  const int f0 = w * 256 + threadIdx.x; // spatial float position
  if (f0 >= HW) return;
  const int ch0 = p * 80 + h * 40;
  const float* cbase = cls + ((size_t)b * 240 + ch0) * HW + f0;
  const unsigned short* up = (const unsigned short*)cbase + 1;   // high half (LE)
  const float* objb = obj + ((size_t)b * 3 + p) * HW;
  const int sub = bx & (SUBS - 1);

  for (int gq = 0; gq < 5; ++gq) {          // 5 groups of 8 channels = 40
    unsigned short hbuf[8];
#pragma unroll
    for (int u = 0; u < 8; ++u)
      hbuf[u] = up[(size_t)(gq * 8 + u) * HW * 2];
#pragma unroll
    for (int u = 0; u < 8; ++u) {
      if ((short)hbuf[u] > (short)HI16_SCREEN) {     // hi16 screen (superset)
        float v = cbase[(size_t)(gq * 8 + u) * HW];  // exact reload (line often L2-hot)
        if (v > SCREEN) {                            // exact logit screen
          float ov = objb[f0];                       // rare-path scalar
          float s = sigm(v) * sigm(ov);              // exact arithmetic (same as ref)
          if (s > T0) {
            uint32_t slot = atomicAdd(&cnt75[b * SUBS + sub], 1u);
            if (slot < SUBCAP) {
              const int c = h * 40 + gq * 8 + u;
              uint32_t flat = (uint32_t)(((cellbase + f0) * 3 + p) * 80 + c);
              cand75[((size_t)(b * SUBS + sub)) * SUBCAP + slot] =
                  ((uint64_t)__float_as_uint(s) << 32) | (uint64_t)(0xFFFFFFFFu - flat);
            }
          }
        }
      }
    }
  }
}

// ---------------- K3: per-image gather + exact top-1000 + decode ----------------
__global__ __launch_bounds__(1024) void k_gather(
    const uint64_t* __restrict__ cand75, const uint32_t* __restrict__ cnt75,
    uint32_t* __restrict__ flags, uint32_t* __restrict__ histg,
    const float* __restrict__ bbox0, const float* __restrict__ bbox1, const float* __restrict__ bbox2,
    const float* __restrict__ priors, const float* __restrict__ strides,
    float* __restrict__ topS, int* __restrict__ topLab, float* __restrict__ topBox,
    uint32_t* __restrict__ nvArr) {
  __shared__ uint32_t hist[GBINS];
  __shared__ uint64_t comp[COMPCAP];
  __shared__ uint32_t seg[64];
  __shared__ uint32_t ncomp_s, cb_s;
  const int b = blockIdx.x;
  const int tid = threadIdx.x;
  uint32_t tot = 0; bool bad = false;
  for (int s = 0; s < SUBS; ++s) {
    uint32_t cc = cnt75[b * SUBS + s];
    tot += cc;
    if (cc > SUBCAP) bad = true;
  }
  if (tot < (uint32_t)PRE) bad = true;
  if (bad) {
    if (tid == 0) flags[b] = 1u;
    for (int i = tid; i < NBINS; i += 1024) histg[(size_t)b * NBINS + i] = 0;
    return;
  }

  for (int i = tid; i < GBINS; i += 1024) hist[i] = 0;
  if (tid == 0) ncomp_s = 0;
  __syncthreads();
  for (int s = 0; s < SUBS; ++s) {
    uint32_t c = cnt75[b * SUBS + s];
    const uint64_t* src = cand75 + ((size_t)(b * SUBS + s)) * SUBCAP;
    for (int i = tid; i < (int)c; i += 1024) {
      uint32_t hi = (uint32_t)(src[i] >> 32);
      uint32_t bin = (hi - 0x3F400000u) >> 10;
      if (bin > GBINS - 1) bin = GBINS - 1;
      atomicAdd(&hist[bin], 1u);
    }
  }
  __syncthreads();
  if (tid < 64) {
    uint32_t s = 0;
    for (int k = 0; k < 64; ++k) s += hist[tid * 64 + k];
    seg[tid] = s;
  }
  __syncthreads();
  if (tid == 0) {
    uint32_t acc = 0; int segi = 0;
    for (int i = 63; i >= 0; --i) {
      if (acc + seg[i] >= (uint32_t)PRE) { segi = i; break; }
      acc += seg[i];
    }
    uint32_t cb = 0;
    for (int k = 63; k >= 0; --k) {
      acc += hist[segi * 64 + k];
      if (acc >= (uint32_t)PRE) { cb = (uint32_t)(segi * 64 + k); break; }
    }
    cb_s = cb;
  }
  __syncthreads();
  const uint32_t cb = cb_s;
  for (int s = 0; s < SUBS; ++s) {
    uint32_t c = cnt75[b * SUBS + s];
    const uint64_t* src = cand75 + ((size_t)(b * SUBS + s)) * SUBCAP;
    for (int i = tid; i < (int)c; i += 1024) {
      uint64_t key = src[i];
      uint32_t hi = (uint32_t)(key >> 32);
      uint32_t bin = (hi - 0x3F400000u) >> 10;
      if (bin > GBINS - 1) bin = GBINS - 1;
      if (bin >= cb) {
        uint32_t pos = atomicAdd(&ncomp_s, 1u);
        if (pos < COMPCAP) comp[pos] = key;
      }
    }
  }
  __syncthreads();
  const uint32_t ncomp = ncomp_s;
  if (ncomp > COMPCAP) {
    if (tid == 0) flags[b] = 1u;
    for (int i = tid; i < NBINS; i += 1024) histg[(size_t)b * NBINS + i] = 0;
    return;
  }
  const int N = (ncomp <= 1024u) ? 1024 : COMPCAP;   // adaptive sort size
  for (int i = tid; i < N; i += 1024) if (i >= (int)ncomp) comp[i] = 0ull;
  __syncthreads();
  for (int k = 2; k <= N; k <<= 1) {
    for (int j = k >> 1; j > 0; j >>= 1) {
      for (int i = tid; i < N; i += 1024) {
        int p = i ^ j;
        if (p > i) {
          uint64_t a = comp[i], c = comp[p];
          bool asc = (i & k) != 0;
          if (asc ? (a > c) : (a < c)) { comp[i] = c; comp[p] = a; }
        }
      }
      __syncthreads();
    }
  }
  if (tid == 0) nvArr[b] = (uint32_t)PRE;
  for (int t = tid; t < PRE; t += 1024) {
    uint64_t key = comp[t];
    float sc = __uint_as_float((uint32_t)(key >> 32));
    uint32_t flat = 0xFFFFFFFFu - (uint32_t)(key & 0xFFFFFFFFull);
    uint32_t n = flat / 80u; int lab = (int)(flat - n * 80u);
    uint32_t g = n / 3u; uint32_t p = n - g * 3u;
    int li, loc, HW; lvlinfo((int)g, li, loc, HW);
    const float* bb = li == 0 ? bbox0 : (li == 1 ? bbox1 : bbox2);
    size_t o = ((size_t)b * 12 + p * 4) * HW + loc;
    float p0 = sigm(bb[o]);
    float p1 = sigm(bb[o + (size_t)HW]);
    float p2 = sigm(bb[o + 2 * (size_t)HW]);
    float p3 = sigm(bb[o + 3 * (size_t)HW]);
    float4 pr = *(const float4*)(priors + (size_t)n * 4);
    float st = strides[n];
    float cx = (pr.x + pr.z) * 0.5f, cy = (pr.y + pr.w) * 0.5f;
    float w = pr.z - pr.x, hh = pr.w - pr.y;
    float xc = (p0 - 0.5f) * 2.0f * st + cx;
    float yc = (p1 - 0.5f) * 2.0f * st + cy;
    float wp = p2 * 2.0f; wp = wp * wp * w;
    float hp = p3 * 2.0f; hp = hp * hp * hh;
    topS[(size_t)b * PRE + t] = sc;
    topLab[(size_t)b * PRE + t] = lab;
    *(float4*)(topBox + ((size_t)b * PRE + t) * 4) =
        make_float4(xc - wp * 0.5f, yc - hp * 0.5f, xc + wp * 0.5f, yc + hp * 0.5f);
  }
}

// ================= FALLBACK PATH (per-image flag; never runs for typical data) ============
__global__ __launch_bounds__(256) void k_hist_fb(
    const float* __restrict__ cls0, const float* __restrict__ cls1, const float* __restrict__ cls2,
    const float* __restrict__ obj0, const float* __restrict__ obj1, const float* __restrict__ obj2,
    uint32_t* __restrict__ hist, const uint32_t* __restrict__ flags,
    uint32_t* __restrict__ histDone, uint32_t* __restrict__ cutoff) {
  const int b = blockIdx.y;
  if (flags[b] == 0u) return;
  __shared__ uint32_t h[NBINS];
  __shared__ uint32_t seg[256];
  __shared__ uint32_t lastArrive;
  for (int i = threadIdx.x; i < NBINS; i += 256) h[i] = 0;
  __syncthreads();
  const int c0 = (blockIdx.x * 256 + threadIdx.x) * 4;
  if (c0 < CELLS) {
    int li, loc, HW; lvlinfo(c0, li, loc, HW);
    const float* cls = li == 0 ? cls0 : (li == 1 ? cls1 : cls2);
    const float* obj = li == 0 ? obj0 : (li == 1 ? obj1 : obj2);
    float os[3][4];
#pragma unroll
    for (int p = 0; p < 3; ++p) {
      float4 o = *(const float4*)(obj + ((size_t)b * 3 + p) * HW + loc);
      os[p][0] = sigm(o.x); os[p][1] = sigm(o.y); os[p][2] = sigm(o.z); os[p][3] = sigm(o.w);
    }
    for (int p = 0; p < 3; ++p) {
      const float* cp = cls + ((size_t)b * 240 + p * 80) * HW + loc;
      for (int c = 0; c < 80; ++c) {
        float4 v = *(const float4*)(cp + (size_t)c * HW);
        float sv[4] = { sigm(v.x) * os[p][0], sigm(v.y) * os[p][1],
                        sigm(v.z) * os[p][2], sigm(v.w) * os[p][3] };
#pragma unroll
        for (int k = 0; k < 4; ++k) {
          if (sv[k] > 0.25f) {
            uint32_t key = (__float_as_uint(sv[k]) - 0x3E800000u) >> 10;
            if (key > NBINS - 1) key = NBINS - 1;
            atomicAdd(&h[key], 1u);
          }
        }
      }
    }
  }
  __syncthreads();
  for (int i = threadIdx.x; i < NBINS; i += 256) {
    uint32_t v = h[i];
    if (v) atomicAdd(&hist[(size_t)b * NBINS + i], v);
  }
  __syncthreads();
  __threadfence();
  if (threadIdx.x == 0) lastArrive = atomicAdd(&histDone[b], 1u);
  __syncthreads();
  if (lastArrive != 8) return;
  __threadfence();
  uint32_t* hb = hist + (size_t)b * NBINS;
  uint32_t s = 0;
  for (int k = 0; k < 64; ++k) s += atomicOr(&hb[threadIdx.x * 64 + k], 0u);
  seg[threadIdx.x] = s;
  __syncthreads();
  if (threadIdx.x == 0) {
    uint32_t acc = 0; int segi = -1;
    for (int i = 255; i >= 0; --i) {
      if (acc + seg[i] >= (uint32_t)PRE) { segi = i; break; }
      acc += seg[i];
    }
    uint32_t cut = 0;
    if (segi >= 0) {
      for (int k = 63; k >= 0; --k) {
        acc += atomicOr(&hb[segi * 64 + k], 0u);
        if (acc >= (uint32_t)PRE) { cut = (uint32_t)(segi * 64 + k); break; }
      }
    }
    cutoff[b] = cut;
  }
}

__global__ __launch_bounds__(256) void k_collect_fb(
    const float* __restrict__ cls0, const float* __restrict__ cls1, const float* __restrict__ cls2,
    const float* __restrict__ obj0, const float* __restrict__ obj1, const float* __restrict__ obj2,
    const uint32_t* __restrict__ cutoff, uint32_t* __restrict__ candCount,
    uint64_t* __restrict__ cand, const uint32_t* __restrict__ flags,
    uint32_t* __restrict__ collectDone,
    const float* __restrict__ bbox0, const float* __restrict__ bbox1, const float* __restrict__ bbox2,
    const float* __restrict__ priors, const float* __restrict__ strides,
    float* __restrict__ topS, int* __restrict__ topLab, float* __restrict__ topBox,
    uint32_t* __restrict__ nvArr) {
  const int b = blockIdx.y;
  if (flags[b] == 0u) return;
  __shared__ uint64_t s[CAP];
  __shared__ uint32_t lastArrive;
  const uint32_t cut = cutoff[b];
  const int c0 = (blockIdx.x * 256 + threadIdx.x) * 4;
  if (c0 < CELLS) {
    int li, loc, HW; lvlinfo(c0, li, loc, HW);
    const float* cls = li == 0 ? cls0 : (li == 1 ? cls1 : cls2);
    const float* obj = li == 0 ? obj0 : (li == 1 ? obj1 : obj2);
    float os[3][4];
#pragma unroll
    for (int p = 0; p < 3; ++p) {
      float4 o = *(const float4*)(obj + ((size_t)b * 3 + p) * HW + loc);
      os[p][0] = sigm(o.x); os[p][1] = sigm(o.y); os[p][2] = sigm(o.z); os[p][3] = sigm(o.w);
    }
    for (int p = 0; p < 3; ++p) {
      const float* cp = cls + ((size_t)b * 240 + p * 80) * HW + loc;
      for (int c = 0; c < 80; ++c) {
        float4 v = *(const float4*)(cp + (size_t)c * HW);
        float sv[4] = { sigm(v.x) * os[p][0], sigm(v.y) * os[p][1],
                        sigm(v.z) * os[p][2], sigm(v.w) * os[p][3] };
#pragma unroll
        for (int k = 0; k < 4; ++k) {
          float sk = sv[k];
          if (sk > 0.25f) {
            uint32_t key = (__float_as_uint(sk) - 0x3E800000u) >> 10;
            if (key >= cut) {
              uint32_t pos = atomicAdd(&candCount[b], 1u);
              if (pos < CAP) {
                uint32_t flat = (uint32_t)((((c0 + k) * 3 + p) * 80) + c);
                cand[(size_t)b * CAP + pos] =
                    ((uint64_t)__float_as_uint(sk) << 32) | (uint64_t)(0xFFFFFFFFu - flat);
              }
            }
          }
        }
      }
    }
  }
  __syncthreads();
  __threadfence();
  if (threadIdx.x == 0) lastArrive = atomicAdd(&collectDone[b], 1u);
  __syncthreads();
  if (lastArrive != 8) return;
  __threadfence();
  uint32_t cnt = atomicOr(&candCount[b], 0u); if (cnt > (uint32_t)CAP) cnt = CAP;
  for (int i = threadIdx.x; i < CAP; i += 256)
    s[i] = (i < (int)cnt) ? cand[(size_t)b * CAP + i] : 0ull;
  __syncthreads();
  for (int k = 2; k <= CAP; k <<= 1) {
    for (int j = k >> 1; j > 0; j >>= 1) {
      for (int i = threadIdx.x; i < CAP; i += 256) {
        int p = i ^ j;
        if (p > i) {
          uint64_t a = s[i], c = s[p];
          bool asc = (i & k) != 0;
          if (asc ? (a > c) : (a < c)) { s[i] = c; s[p] = a; }
        }
      }
      __syncthreads();
    }
  }
  const int NV = (int)(cnt < (uint32_t)PRE ? cnt : (uint32_t)PRE);
  if (threadIdx.x == 0) nvArr[b] = (uint32_t)NV;
  for (int t = threadIdx.x; t < PRE; t += 256) {
    float sc = 0.0f; int lab = 0; float b0 = 0, b1 = 0, b2v = 0, b3 = 0;
    if (t < NV) {
      uint64_t key = s[t];
      sc = __uint_as_float((uint32_t)(key >> 32));
      uint32_t flat = 0xFFFFFFFFu - (uint32_t)(key & 0xFFFFFFFFull);
      uint32_t n = flat / 80u; lab = (int)(flat - n * 80u);
      uint32_t g = n / 3u; uint32_t p = n - g * 3u;
      int li, loc, HW; lvlinfo((int)g, li, loc, HW);
      const float* bb = li == 0 ? bbox0 : (li == 1 ? bbox1 : bbox2);
      size_t o = ((size_t)b * 12 + p * 4) * HW + loc;
      float p0 = sigm(bb[o]);
      float p1 = sigm(bb[o + (size_t)HW]);
      float p2 = sigm(bb[o + 2 * (size_t)HW]);
      float p3 = sigm(bb[o + 3 * (size_t)HW]);
      float4 pr = *(const float4*)(priors + (size_t)n * 4);
      float st = strides[n];
      float cx = (pr.x + pr.z) * 0.5f, cy = (pr.y + pr.w) * 0.5f;
      float w = pr.z - pr.x, hh = pr.w - pr.y;
      float xc = (p0 - 0.5f) * 2.0f * st + cx;
      float yc = (p1 - 0.5f) * 2.0f * st + cy;
      float wp = p2 * 2.0f; wp = wp * wp * w;
      float hp = p3 * 2.0f; hp = hp * hp * hh;
      b0 = xc - wp * 0.5f; b1 = yc - hp * 0.5f; b2v = xc + wp * 0.5f; b3 = yc + hp * 0.5f;
    }
    topS[(size_t)b * PRE + t] = sc;
    topLab[(size_t)b * PRE + t] = lab;
    *(float4*)(topBox + ((size_t)b * PRE + t) * 4) = make_float4(b0, b1, b2v, b3);
  }
}

// ---------------- K5: IoU suppression bitmask (63 blocks/image) ----------------
__global__ __launch_bounds__(256) void k_iou(
    const float* __restrict__ topBox, const int* __restrict__ topLab,
    const uint32_t* __restrict__ nvArr, uint64_t* __restrict__ mask) {
  __shared__ float4 bx[PRE];
  __shared__ int lb[PRE];
  const int b = blockIdx.y;
  const int NV = (int)nvArr[b];
  for (int i = threadIdx.x; i < PRE; i += 256) {
    bx[i] = *(const float4*)(topBox + ((size_t)b * PRE + i) * 4);
    lb[i] = topLab[(size_t)b * PRE + i];
  }
  __syncthreads();
  for (int task = blockIdx.x * 256 + threadIdx.x; task < PRE * 16; task += gridDim.x * 256) {
    const int i = task >> 4, w = task & 15;
    uint64_t m = 0;
    if (i < NV) {
      const float4 a = bx[i]; const int la = lb[i];
      const float areaA = (a.z - a.x) * (a.w - a.y);
      const int j0 = w << 6;
      const int jend = (j0 + 64 < NV) ? j0 + 64 : NV;
      for (int j = (j0 > i + 1 ? j0 : i + 1); j < jend; ++j) {
        if (lb[j] != la) continue;
        const float4 c = bx[j];
        float xx1 = fmaxf(a.x, c.x), yy1 = fmaxf(a.y, c.y);
        float xx2 = fminf(a.z, c.z), yy2 = fminf(a.w, c.w);
        float iw = fmaxf(xx2 - xx1, 0.0f), ih = fmaxf(yy2 - yy1, 0.0f);
        float inter = iw * ih;
        float areaB = (c.z - c.x) * (c.w - c.y);
        float iou = inter / (areaA + areaB - inter + 1e-7f);
        if (iou > 0.65f) m |= (1ull << (j - j0));
      }
    }
    mask[((size_t)b * PRE + i) * 16 + w] = m;
  }
}

// ---------------- K6: serial greedy scan (branchless, pipelined) + output assembly --------
__global__ __launch_bounds__(256) void k_scan_out(
    const uint64_t* __restrict__ mask, const float* __restrict__ topS,
    const int* __restrict__ topLab, const float* __restrict__ topBox,
    const uint32_t* __restrict__ nvArr, float* __restrict__ out) {
  __shared__ uint64_t rows[PRE * 16];   // 125 KB
  __shared__ uint64_t keepw[16];
  __shared__ uint32_t pref[17];
  const int b = blockIdx.x;
  const int NV = (int)nvArr[b];
  for (int i = threadIdx.x; i < NV * 16; i += 256) rows[i] = mask[(size_t)b * PRE * 16 + i];
  __syncthreads();
  if (threadIdx.x < 64) {
    const int lane = threadIdx.x;
    uint64_t remv = 0, kw = 0;
    for (int w0 = 0; w0 * 64 < NV; ++w0) {
      uint64_t cur = (uint64_t)__shfl((unsigned long long)remv, w0);
      const int ie = (w0 * 64 + 64 < NV) ? w0 * 64 + 64 : NV;
      for (int i = w0 * 64; i < ie; ++i) {
        const int bi = i & 63;
        uint64_t rl = rows[i * 16 + (lane & 15)];
        uint64_t cw = rows[i * 16 + w0];
        const uint64_t keepm = ((cur >> bi) & 1ull) ? 0ull : ~0ull;
        cur |= cw & keepm;
        remv |= rl & keepm;
        kw |= (lane == w0) ? ((1ull << bi) & keepm) : 0ull;
      }
    }
    if (lane < 16) keepw[lane] = kw;
  }
  __syncthreads();
  if (threadIdx.x == 0) {
    uint32_t a = 0;
    for (int w = 0; w < 16; ++w) { pref[w] = a; a += (uint32_t)__popcll((unsigned long long)keepw[w]); }
    pref[16] = a;
  }
  __syncthreads();
  const uint32_t total = pref[16];
  const uint32_t num = total < (uint32_t)KEEP ? total : (uint32_t)KEEP;
  float* o_num = out;
  float* o_box = out + NIMG;
  float* o_s   = out + NIMG + NIMG * KEEP * 4;
  float* o_l   = o_s + NIMG * KEEP;
  if (threadIdx.x == 0) o_num[b] = (float)num;
  const int zstart = NV < KEEP ? NV : KEEP;
  for (int sidx = zstart + threadIdx.x; sidx < KEEP; sidx += 256) {
    ((float4*)o_box)[b * KEEP + sidx] = make_float4(0, 0, 0, 0);
    o_s[b * KEEP + sidx] = 0.0f;
    o_l[b * KEEP + sidx] = 0.0f;
  }
  for (int j = threadIdx.x; j < NV; j += 256) {
    const int wi = j >> 6, bi = j & 63;
    const uint64_t kword = keepw[wi];
    const int isk = (int)((kword >> bi) & 1ull);
    const uint32_t below = pref[wi] + (uint32_t)__popcll((unsigned long long)(kword & ((1ull << bi) - 1ull)));
    const uint32_t slot = isk ? below : (total + (uint32_t)j - below);
    if (slot < (uint32_t)KEEP) {
      ((float4*)o_box)[b * KEEP + slot] = *(const float4*)(topBox + ((size_t)b * PRE + j) * 4);
      o_s[b * KEEP + slot] = isk ? topS[(size_t)b * PRE + j] : 0.0f;
      o_l[b * KEEP + slot] = (float)topLab[(size_t)b * PRE + j];
    }
  }
}

extern "C" void kernel_launch(void* const* d_in, const int* in_sizes, int n_in,
                              void* d_out, int out_size, void* d_ws, size_t ws_size,
                              hipStream_t stream) {
  (void)in_sizes; (void)n_in; (void)out_size; (void)ws_size;
  const float* cls0 = (const float*)d_in[0];
  const float* cls1 = (const float*)d_in[1];
  const float* cls2 = (const float*)d_in[2];
  const float* bbox0 = (const float*)d_in[3];
  const float* bbox1 = (const float*)d_in[4];
  const float* bbox2 = (const float*)d_in[5];
  const float* obj0 = (const float*)d_in[6];
  const float* obj1 = (const float*)d_in[7];
  const float* obj2 = (const float*)d_in[8];
  const float* priors = (const float*)d_in[9];
  const float* strides = (const float*)d_in[10];
  float* out = (float*)d_out;

  char* ws = (char*)d_ws;
  size_t off = 0;
  auto alloc = [&](size_t bytes) -> void* {
    void* p = ws + off;
    off = (off + bytes + 255) & ~(size_t)255;
    return p;
  };
  uint32_t* small       = (uint32_t*)alloc(4096);
  uint32_t* flags       = small;                 // [32]
  uint32_t* cnt75       = small + 32;            // [256]
  uint32_t* candCount   = small + 288;           // [32]
  uint32_t* cutoff      = small + 320;           // [32]
  uint32_t* nvArr       = small + 352;           // [32]
  uint32_t* histDone    = small + 384;           // [32]
  uint32_t* collectDone = small + 416;           // [32]
  uint64_t* cand75    = (uint64_t*)alloc((size_t)NIMG * SUBS * SUBCAP * 8); // 4 MB
  uint32_t* hist      = (uint32_t*)alloc((size_t)NIMG * NBINS * 4);         // 2 MB (fb)
  uint64_t* cand      = (uint64_t*)alloc((size_t)NIMG * CAP * 8);           // 1 MB (fb)
  float*    topS      = (float*)alloc((size_t)NIMG * PRE * 4);
  int*      topLab    = (int*)alloc((size_t)NIMG * PRE * 4);
  float*    topBox    = (float*)alloc((size_t)NIMG * PRE * 16);
  uint64_t* maskbuf   = (uint64_t*)alloc((size_t)NIMG * PRE * 16 * 8);      // 4 MB

  hipMemsetAsync(small, 0, 4096, stream);

  k_pass1<<<dim3(204, NIMG), 256, 0, stream>>>(cls0, cls1, cls2, obj0, obj1, obj2,
                                               cnt75, cand75);
  k_gather<<<NIMG, 1024, 0, stream>>>(cand75, cnt75, flags, hist, bbox0, bbox1, bbox2,
                                      priors, strides, topS, topLab, topBox, nvArr);
  dim3 gScan(9, NIMG);
  k_hist_fb<<<gScan, 256, 0, stream>>>(cls0, cls1, cls2, obj0, obj1, obj2, hist, flags,
                                       histDone, cutoff);
  k_collect_fb<<<gScan, 256, 0, stream>>>(cls0, cls1, cls2, obj0, obj1, obj2,
                                          cutoff, candCount, cand, flags, collectDone,
                                          bbox0, bbox1, bbox2, priors, strides,
                                          topS, topLab, topBox, nvArr);
  k_iou<<<dim3(63, NIMG), 256, 0, stream>>>(topBox, topLab, nvArr, maskbuf);
  k_scan_out<<<NIMG, 256, 0, stream>>>(maskbuf, topS, topLab, topBox, nvArr, out);
}

// Round 15
// 368.982 us; speedup vs baseline: 2.3345x; 1.6897x over previous
//
#include <hip/hip_runtime.h>
#include <stdint.h>

#define NCLS 80
#define CELLS 8400      // 6400 + 1600 + 400
#define PRE 1000
#define KEEP 100
#define CAP 4096        // fallback candidate cap
#define NBINS 16384     // fallback histogram bins
#define NIMG 32
#define SUBS 8
#define SUBCAP 2048     // per-sub store cap (total 16384/image)
#define GBINS 4096      // gather-phase LDS histogram bins
#define COMPCAP 2048
#define T0 0.75f        // static pre-store threshold (top-1000 cutoff ~0.82 for N(0,1))
#define SCREEN 1.0886f  // logit(0.75)=1.0986 minus slack; exact test done on sigm product

__device__ __forceinline__ float sigm(float x) { return 1.0f / (1.0f + __expf(-x)); }

__device__ __forceinline__ void lvlinfo(int cell, int& li, int& loc, int& HW) {
  if (cell < 6400)      { li = 0; loc = cell;        HW = 6400; }
  else if (cell < 8000) { li = 1; loc = cell - 6400; HW = 1600; }
  else                  { li = 2; loc = cell - 8000; HW = 400;  }
}

// ---------------- K1: R11 mapping + single-asm-block FORCED depth-8 loads ----------------
// Grid (54, NIMG). Thread owns one float4 position and 40 channels (5 batches of 8).
// All 8 global_load_dwordx4 AND the s_waitcnt live in ONE asm block: the compiler
// cannot fuse/split/remat -> guaranteed 8 loads in flight per wave per round.
// "=&v" early-clobber keeps dest regs disjoint from the 64-bit address inputs.
__global__ __launch_bounds__(256) void k_pass1(
    const float* __restrict__ cls0, const float* __restrict__ cls1, const float* __restrict__ cls2,
    const float* __restrict__ obj0, const float* __restrict__ obj1, const float* __restrict__ obj2,
    uint32_t* __restrict__ cnt75, uint64_t* __restrict__ cand75) {
  const int b = blockIdx.y;
  const int bx = blockIdx.x;
  const int sb = bx / 6;                // 9 spatial blocks
  const int r  = bx - sb * 6;
  const int h  = r & 1;                 // class half: [h*40, h*40+40)
  const int p  = r >> 1;                // prior 0..2
  const int c0cell = (sb * 256 + threadIdx.x) * 4;
  if (c0cell >= CELLS) return;
  int li, loc, HW; lvlinfo(c0cell, li, loc, HW);
  const float* cls = li == 0 ? cls0 : (li == 1 ? cls1 : cls2);
  const float* obj = li == 0 ? obj0 : (li == 1 ? obj1 : obj2);

  float4 ov = *(const float4*)(obj + ((size_t)b * 3 + p) * HW + loc);
  float os[4] = { sigm(ov.x), sigm(ov.y), sigm(ov.z), sigm(ov.w) };

  const int sub = bx & (SUBS - 1);
  const float* cp = cls + ((size_t)b * 240 + p * 80 + h * 40) * HW + loc;

  for (int gq = 0; gq < 5; ++gq) {          // 5 groups of 8 classes = 40
    float4 v0, v1, v2, v3, v4, v5, v6, v7;
    const float* a0 = cp + (size_t)(gq * 8 + 0) * HW;
    const float* a1 = cp + (size_t)(gq * 8 + 1) * HW;
    const float* a2 = cp + (size_t)(gq * 8 + 2) * HW;
    const float* a3 = cp + (size_t)(gq * 8 + 3) * HW;
    const float* a4 = cp + (size_t)(gq * 8 + 4) * HW;
    const float* a5 = cp + (size_t)(gq * 8 + 5) * HW;
    const float* a6 = cp + (size_t)(gq * 8 + 6) * HW;
    const float* a7 = cp + (size_t)(gq * 8 + 7) * HW;
    asm volatile(
        "global_load_dwordx4 %0, %8, off\n\t"
        "global_load_dwordx4 %1, %9, off\n\t"
        "global_load_dwordx4 %2, %10, off\n\t"
        "global_load_dwordx4 %3, %11, off\n\t"
        "global_load_dwordx4 %4, %12, off\n\t"
        "global_load_dwordx4 %5, %13, off\n\t"
        "global_load_dwordx4 %6, %14, off\n\t"
        "global_load_dwordx4 %7, %15, off\n\t"
        "s_waitcnt vmcnt(0)"
        : "=&v"(v0), "=&v"(v1), "=&v"(v2), "=&v"(v3),
          "=&v"(v4), "=&v"(v5), "=&v"(v6), "=&v"(v7)
        : "v"(a0), "v"(a1), "v"(a2), "v"(a3),
          "v"(a4), "v"(a5), "v"(a6), "v"(a7));
    __builtin_amdgcn_sched_barrier(0);

    float4 vv8[8] = { v0, v1, v2, v3, v4, v5, v6, v7 };
#pragma unroll
    for (int u = 0; u < 8; ++u) {
      const int c = h * 40 + gq * 8 + u;    // class within prior, 0..79
      float vv[4] = { vv8[u].x, vv8[u].y, vv8[u].z, vv8[u].w };
#pragma unroll
      for (int k = 0; k < 4; ++k) {
        if (vv[k] > SCREEN) {               // conservative logit screen (no exp for ~86%)
          float s = sigm(vv[k]) * os[k];    // exact arithmetic (same as ref path)
          if (s > T0) {
            uint32_t slot = atomicAdd(&cnt75[b * SUBS + sub], 1u);
            if (slot < SUBCAP) {
              uint32_t flat = (uint32_t)(((c0cell + k) * 3 + p) * 80 + c);
              cand75[((size_t)(b * SUBS + sub)) * SUBCAP + slot] =
                  ((uint64_t)__float_as_uint(s) << 32) | (uint64_t)(0xFFFFFFFFu - flat);
            }
          }
        }
      }
    }
  }
}

// ---------------- K3: per-image gather + exact top-1000 + decode ----------------
__global__ __launch_bounds__(1024) void k_gather(
    const uint64_t* __restrict__ cand75, const uint32_t* __restrict__ cnt75,
    uint32_t* __restrict__ flags, uint32_t* __restrict__ histg,
    const float* __restrict__ bbox0, const float* __restrict__ bbox1, const float* __restrict__ bbox2,
    const float* __restrict__ priors, const float* __restrict__ strides,
    float* __restrict__ topS, int* __restrict__ topLab, float* __restrict__ topBox,
    uint32_t* __restrict__ nvArr) {
  __shared__ uint32_t hist[GBINS];
  __shared__ uint64_t comp[COMPCAP];
  __shared__ uint32_t seg[64];
  __shared__ uint32_t ncomp_s, cb_s;
  const int b = blockIdx.x;
  const int tid = threadIdx.x;
  uint32_t tot = 0; bool bad = false;
  for (int s = 0; s < SUBS; ++s) {
    uint32_t cc = cnt75[b * SUBS + s];
    tot += cc;
    if (cc > SUBCAP) bad = true;
  }
  if (tot < (uint32_t)PRE) bad = true;
  if (bad) {
    if (tid == 0) flags[b] = 1u;
    for (int i = tid; i < NBINS; i += 1024) histg[(size_t)b * NBINS + i] = 0;
    return;
  }

  for (int i = tid; i < GBINS; i += 1024) hist[i] = 0;
  if (tid == 0) ncomp_s = 0;
  __syncthreads();
  for (int s = 0; s < SUBS; ++s) {
    uint32_t c = cnt75[b * SUBS + s];
    const uint64_t* src = cand75 + ((size_t)(b * SUBS + s)) * SUBCAP;
    for (int i = tid; i < (int)c; i += 1024) {
      uint32_t hi = (uint32_t)(src[i] >> 32);
      uint32_t bin = (hi - 0x3F400000u) >> 10;
      if (bin > GBINS - 1) bin = GBINS - 1;
      atomicAdd(&hist[bin], 1u);
    }
  }
  __syncthreads();
  if (tid < 64) {
    uint32_t s = 0;
    for (int k = 0; k < 64; ++k) s += hist[tid * 64 + k];
    seg[tid] = s;
  }
  __syncthreads();
  if (tid == 0) {
    uint32_t acc = 0; int segi = 0;
    for (int i = 63; i >= 0; --i) {
      if (acc + seg[i] >= (uint32_t)PRE) { segi = i; break; }
      acc += seg[i];
    }
    uint32_t cb = 0;
    for (int k = 63; k >= 0; --k) {
      acc += hist[segi * 64 + k];
      if (acc >= (uint32_t)PRE) { cb = (uint32_t)(segi * 64 + k); break; }
    }
    cb_s = cb;
  }
  __syncthreads();
  const uint32_t cb = cb_s;
  for (int s = 0; s < SUBS; ++s) {
    uint32_t c = cnt75[b * SUBS + s];
    const uint64_t* src = cand75 + ((size_t)(b * SUBS + s)) * SUBCAP;
    for (int i = tid; i < (int)c; i += 1024) {
      uint64_t key = src[i];
      uint32_t hi = (uint32_t)(key >> 32);
      uint32_t bin = (hi - 0x3F400000u) >> 10;
      if (bin > GBINS - 1) bin = GBINS - 1;
      if (bin >= cb) {
        uint32_t pos = atomicAdd(&ncomp_s, 1u);
        if (pos < COMPCAP) comp[pos] = key;
      }
    }
  }
  __syncthreads();
  const uint32_t ncomp = ncomp_s;
  if (ncomp > COMPCAP) {
    if (tid == 0) flags[b] = 1u;
    for (int i = tid; i < NBINS; i += 1024) histg[(size_t)b * NBINS + i] = 0;
    return;
  }
  const int N = (ncomp <= 1024u) ? 1024 : COMPCAP;   // adaptive sort size
  for (int i = tid; i < N; i += 1024) if (i >= (int)ncomp) comp[i] = 0ull;
  __syncthreads();
  for (int k = 2; k <= N; k <<= 1) {
    for (int j = k >> 1; j > 0; j >>= 1) {
      for (int i = tid; i < N; i += 1024) {
        int p = i ^ j;
        if (p > i) {
          uint64_t a = comp[i], c = comp[p];
          bool asc = (i & k) != 0;
          if (asc ? (a > c) : (a < c)) { comp[i] = c; comp[p] = a; }
        }
      }
      __syncthreads();
    }
  }
  if (tid == 0) nvArr[b] = (uint32_t)PRE;
  for (int t = tid; t < PRE; t += 1024) {
    uint64_t key = comp[t];
    float sc = __uint_as_float((uint32_t)(key >> 32));
    uint32_t flat = 0xFFFFFFFFu - (uint32_t)(key & 0xFFFFFFFFull);
    uint32_t n = flat / 80u; int lab = (int)(flat - n * 80u);
    uint32_t g = n / 3u; uint32_t p = n - g * 3u;
    int li, loc, HW; lvlinfo((int)g, li, loc, HW);
    const float* bb = li == 0 ? bbox0 : (li == 1 ? bbox1 : bbox2);
    size_t o = ((size_t)b * 12 + p * 4) * HW + loc;
    float p0 = sigm(bb[o]);
    float p1 = sigm(bb[o + (size_t)HW]);
    float p2 = sigm(bb[o + 2 * (size_t)HW]);
    float p3 = sigm(bb[o + 3 * (size_t)HW]);
    float4 pr = *(const float4*)(priors + (size_t)n * 4);
    float st = strides[n];
    float cx = (pr.x + pr.z) * 0.5f, cy = (pr.y + pr.w) * 0.5f;
    float w = pr.z - pr.x, hh = pr.w - pr.y;
    float xc = (p0 - 0.5f) * 2.0f * st + cx;
    float yc = (p1 - 0.5f) * 2.0f * st + cy;
    float wp = p2 * 2.0f; wp = wp * wp * w;
    float hp = p3 * 2.0f; hp = hp * hp * hh;
    topS[(size_t)b * PRE + t] = sc;
    topLab[(size_t)b * PRE + t] = lab;
    *(float4*)(topBox + ((size_t)b * PRE + t) * 4) =
        make_float4(xc - wp * 0.5f, yc - hp * 0.5f, xc + wp * 0.5f, yc + hp * 0.5f);
  }
}

// ================= FALLBACK PATH (per-image flag; never runs for typical data) ============
__global__ __launch_bounds__(256) void k_hist_fb(
    const float* __restrict__ cls0, const float* __restrict__ cls1, const float* __restrict__ cls2,
    const float* __restrict__ obj0, const float* __restrict__ obj1, const float* __restrict__ obj2,
    uint32_t* __restrict__ hist, const uint32_t* __restrict__ flags,
    uint32_t* __restrict__ histDone, uint32_t* __restrict__ cutoff) {
  const int b = blockIdx.y;
  if (flags[b] == 0u) return;
  __shared__ uint32_t h[NBINS];
  __shared__ uint32_t seg[256];
  __shared__ uint32_t lastArrive;
  for (int i = threadIdx.x; i < NBINS; i += 256) h[i] = 0;
  __syncthreads();
  const int c0 = (blockIdx.x * 256 + threadIdx.x) * 4;
  if (c0 < CELLS) {
    int li, loc, HW; lvlinfo(c0, li, loc, HW);
    const float* cls = li == 0 ? cls0 : (li == 1 ? cls1 : cls2);
    const float* obj = li == 0 ? obj0 : (li == 1 ? obj1 : obj2);
    float os[3][4];
#pragma unroll
    for (int p = 0; p < 3; ++p) {
      float4 o = *(const float4*)(obj + ((size_t)b * 3 + p) * HW + loc);
      os[p][0] = sigm(o.x); os[p][1] = sigm(o.y); os[p][2] = sigm(o.z); os[p][3] = sigm(o.w);
    }
    for (int p = 0; p < 3; ++p) {
      const float* cp = cls + ((size_t)b * 240 + p * 80) * HW + loc;
      for (int c = 0; c < 80; ++c) {
        float4 v = *(const float4*)(cp + (size_t)c * HW);
        float sv[4] = { sigm(v.x) * os[p][0], sigm(v.y) * os[p][1],
                        sigm(v.z) * os[p][2], sigm(v.w) * os[p][3] };
#pragma unroll
        for (int k = 0; k < 4; ++k) {
          if (sv[k] > 0.25f) {
            uint32_t key = (__float_as_uint(sv[k]) - 0x3E800000u) >> 10;
            if (key > NBINS - 1) key = NBINS - 1;
            atomicAdd(&h[key], 1u);
          }
        }
      }
    }
  }
  __syncthreads();
  for (int i = threadIdx.x; i < NBINS; i += 256) {
    uint32_t v = h[i];
    if (v) atomicAdd(&hist[(size_t)b * NBINS + i], v);
  }
  __syncthreads();
  __threadfence();
  if (threadIdx.x == 0) lastArrive = atomicAdd(&histDone[b], 1u);
  __syncthreads();
  if (lastArrive != 8) return;
  __threadfence();
  uint32_t* hb = hist + (size_t)b * NBINS;
  uint32_t s = 0;
  for (int k = 0; k < 64; ++k) s += atomicOr(&hb[threadIdx.x * 64 + k], 0u);
  seg[threadIdx.x] = s;
  __syncthreads();
  if (threadIdx.x == 0) {
    uint32_t acc = 0; int segi = -1;
    for (int i = 255; i >= 0; --i) {
      if (acc + seg[i] >= (uint32_t)PRE) { segi = i; break; }
      acc += seg[i];
    }
    uint32_t cut = 0;
    if (segi >= 0) {
      for (int k = 63; k >= 0; --k) {
        acc += atomicOr(&hb[segi * 64 + k], 0u);
        if (acc >= (uint32_t)PRE) { cut = (uint32_t)(segi * 64 + k); break; }
      }
    }
    cutoff[b] = cut;
  }
}

__global__ __launch_bounds__(256) void k_collect_fb(
    const float* __restrict__ cls0, const float* __restrict__ cls1, const float* __restrict__ cls2,
    const float* __restrict__ obj0, const float* __restrict__ obj1, const float* __restrict__ obj2,
    const uint32_t* __restrict__ cutoff, uint32_t* __restrict__ candCount,
    uint64_t* __restrict__ cand, const uint32_t* __restrict__ flags,
    uint32_t* __restrict__ collectDone,
    const float* __restrict__ bbox0, const float* __restrict__ bbox1, const float* __restrict__ bbox2,
    const float* __restrict__ priors, const float* __restrict__ strides,
    float* __restrict__ topS, int* __restrict__ topLab, float* __restrict__ topBox,
    uint32_t* __restrict__ nvArr) {
  const int b = blockIdx.y;
  if (flags[b] == 0u) return;
  __shared__ uint64_t s[CAP];
  __shared__ uint32_t lastArrive;
  const uint32_t cut = cutoff[b];
  const int c0 = (blockIdx.x * 256 + threadIdx.x) * 4;
  if (c0 < CELLS) {
    int li, loc, HW; lvlinfo(c0, li, loc, HW);
    const float* cls = li == 0 ? cls0 : (li == 1 ? cls1 : cls2);
    const float* obj = li == 0 ? obj0 : (li == 1 ? obj1 : obj2);
    float os[3][4];
#pragma unroll
    for (int p = 0; p < 3; ++p) {
      float4 o = *(const float4*)(obj + ((size_t)b * 3 + p) * HW + loc);
      os[p][0] = sigm(o.x); os[p][1] = sigm(o.y); os[p][2] = sigm(o.z); os[p][3] = sigm(o.w);
    }
    for (int p = 0; p < 3; ++p) {
      const float* cp = cls + ((size_t)b * 240 + p * 80) * HW + loc;
      for (int c = 0; c < 80; ++c) {
        float4 v = *(const float4*)(cp + (size_t)c * HW);
        float sv[4] = { sigm(v.x) * os[p][0], sigm(v.y) * os[p][1],
                        sigm(v.z) * os[p][2], sigm(v.w) * os[p][3] };
#pragma unroll
        for (int k = 0; k < 4; ++k) {
          float sk = sv[k];
          if (sk > 0.25f) {
            uint32_t key = (__float_as_uint(sk) - 0x3E800000u) >> 10;
            if (key >= cut) {
              uint32_t pos = atomicAdd(&candCount[b], 1u);
              if (pos < CAP) {
                uint32_t flat = (uint32_t)((((c0 + k) * 3 + p) * 80) + c);
                cand[(size_t)b * CAP + pos] =
                    ((uint64_t)__float_as_uint(sk) << 32) | (uint64_t)(0xFFFFFFFFu - flat);
              }
            }
          }
        }
      }
    }
  }
  __syncthreads();
  __threadfence();
  if (threadIdx.x == 0) lastArrive = atomicAdd(&collectDone[b], 1u);
  __syncthreads();
  if (lastArrive != 8) return;
  __threadfence();
  uint32_t cnt = atomicOr(&candCount[b], 0u); if (cnt > (uint32_t)CAP) cnt = CAP;
  for (int i = threadIdx.x; i < CAP; i += 256)
    s[i] = (i < (int)cnt) ? cand[(size_t)b * CAP + i] : 0ull;
  __syncthreads();
  for (int k = 2; k <= CAP; k <<= 1) {
    for (int j = k >> 1; j > 0; j >>= 1) {
      for (int i = threadIdx.x; i < CAP; i += 256) {
        int p = i ^ j;
        if (p > i) {
          uint64_t a = s[i], c = s[p];
          bool asc = (i & k) != 0;
          if (asc ? (a > c) : (a < c)) { s[i] = c; s[p] = a; }
        }
      }
      __syncthreads();
    }
  }
  const int NV = (int)(cnt < (uint32_t)PRE ? cnt : (uint32_t)PRE);
  if (threadIdx.x == 0) nvArr[b] = (uint32_t)NV;
  for (int t = threadIdx.x; t < PRE; t += 256) {
    float sc = 0.0f; int lab = 0; float b0 = 0, b1 = 0, b2v = 0, b3 = 0;
    if (t < NV) {
      uint64_t key = s[t];
      sc = __uint_as_float((uint32_t)(key >> 32));
      uint32_t flat = 0xFFFFFFFFu - (uint32_t)(key & 0xFFFFFFFFull);
      uint32_t n = flat / 80u; lab = (int)(flat - n * 80u);
      uint32_t g = n / 3u; uint32_t p = n - g * 3u;
      int li, loc, HW; lvlinfo((int)g, li, loc, HW);
      const float* bb = li == 0 ? bbox0 : (li == 1 ? bbox1 : bbox2);
      size_t o = ((size_t)b * 12 + p * 4) * HW + loc;
      float p0 = sigm(bb[o]);
      float p1 = sigm(bb[o + (size_t)HW]);
      float p2 = sigm(bb[o + 2 * (size_t)HW]);
      float p3 = sigm(bb[o + 3 * (size_t)HW]);
      float4 pr = *(const float4*)(priors + (size_t)n * 4);
      float st = strides[n];
      float cx = (pr.x + pr.z) * 0.5f, cy = (pr.y + pr.w) * 0.5f;
      float w = pr.z - pr.x, hh = pr.w - pr.y;
      float xc = (p0 - 0.5f) * 2.0f * st + cx;
      float yc = (p1 - 0.5f) * 2.0f * st + cy;
      float wp = p2 * 2.0f; wp = wp * wp * w;
      float hp = p3 * 2.0f; hp = hp * hp * hh;
      b0 = xc - wp * 0.5f; b1 = yc - hp * 0.5f; b2v = xc + wp * 0.5f; b3 = yc + hp * 0.5f;
    }
    topS[(size_t)b * PRE + t] = sc;
    topLab[(size_t)b * PRE + t] = lab;
    *(float4*)(topBox + ((size_t)b * PRE + t) * 4) = make_float4(b0, b1, b2v, b3);
  }
}

// ---------------- K5: IoU suppression bitmask (63 blocks/image) ----------------
__global__ __launch_bounds__(256) void k_iou(
    const float* __restrict__ topBox, const int* __restrict__ topLab,
    const uint32_t* __restrict__ nvArr, uint64_t* __restrict__ mask) {
  __shared__ float4 bx[PRE];
  __shared__ int lb[PRE];
  const int b = blockIdx.y;
  const int NV = (int)nvArr[b];
  for (int i = threadIdx.x; i < PRE; i += 256) {
    bx[i] = *(const float4*)(topBox + ((size_t)b * PRE + i) * 4);
    lb[i] = topLab[(size_t)b * PRE + i];
  }
  __syncthreads();
  for (int task = blockIdx.x * 256 + threadIdx.x; task < PRE * 16; task += gridDim.x * 256) {
    const int i = task >> 4, w = task & 15;
    uint64_t m = 0;
    if (i < NV) {
      const float4 a = bx[i]; const int la = lb[i];
      const float areaA = (a.z - a.x) * (a.w - a.y);
      const int j0 = w << 6;
      const int jend = (j0 + 64 < NV) ? j0 + 64 : NV;
      for (int j = (j0 > i + 1 ? j0 : i + 1); j < jend; ++j) {
        if (lb[j] != la) continue;
        const float4 c = bx[j];
        float xx1 = fmaxf(a.x, c.x), yy1 = fmaxf(a.y, c.y);
        float xx2 = fminf(a.z, c.z), yy2 = fminf(a.w, c.w);
        float iw = fmaxf(xx2 - xx1, 0.0f), ih = fmaxf(yy2 - yy1, 0.0f);
        float inter = iw * ih;
        float areaB = (c.z - c.x) * (c.w - c.y);
        float iou = inter / (areaA + areaB - inter + 1e-7f);
        if (iou > 0.65f) m |= (1ull << (j - j0));
      }
    }
    mask[((size_t)b * PRE + i) * 16 + w] = m;
  }
}

// ---------------- K6: serial greedy scan (branchless, pipelined) + output assembly --------
__global__ __launch_bounds__(256) void k_scan_out(
    const uint64_t* __restrict__ mask, const float* __restrict__ topS,
    const int* __restrict__ topLab, const float* __restrict__ topBox,
    const uint32_t* __restrict__ nvArr, float* __restrict__ out) {
  __shared__ uint64_t rows[PRE * 16];   // 125 KB
  __shared__ uint64_t keepw[16];
  __shared__ uint32_t pref[17];
  const int b = blockIdx.x;
  const int NV = (int)nvArr[b];
  for (int i = threadIdx.x; i < NV * 16; i += 256) rows[i] = mask[(size_t)b * PRE * 16 + i];
  __syncthreads();
  if (threadIdx.x < 64) {
    const int lane = threadIdx.x;
    uint64_t remv = 0, kw = 0;
    for (int w0 = 0; w0 * 64 < NV; ++w0) {
      uint64_t cur = (uint64_t)__shfl((unsigned long long)remv, w0);
      const int ie = (w0 * 64 + 64 < NV) ? w0 * 64 + 64 : NV;
      for (int i = w0 * 64; i < ie; ++i) {
        const int bi = i & 63;
        uint64_t rl = rows[i * 16 + (lane & 15)];
        uint64_t cw = rows[i * 16 + w0];
        const uint64_t keepm = ((cur >> bi) & 1ull) ? 0ull : ~0ull;
        cur |= cw & keepm;
        remv |= rl & keepm;
        kw |= (lane == w0) ? ((1ull << bi) & keepm) : 0ull;
      }
    }
    if (lane < 16) keepw[lane] = kw;
  }
  __syncthreads();
  if (threadIdx.x == 0) {
    uint32_t a = 0;
    for (int w = 0; w < 16; ++w) { pref[w] = a; a += (uint32_t)__popcll((unsigned long long)keepw[w]); }
    pref[16] = a;
  }
  __syncthreads();
  const uint32_t total = pref[16];
  const uint32_t num = total < (uint32_t)KEEP ? total : (uint32_t)KEEP;
  float* o_num = out;
  float* o_box = out + NIMG;
  float* o_s   = out + NIMG + NIMG * KEEP * 4;
  float* o_l   = o_s + NIMG * KEEP;
  if (threadIdx.x == 0) o_num[b] = (float)num;
  const int zstart = NV < KEEP ? NV : KEEP;
  for (int sidx = zstart + threadIdx.x; sidx < KEEP; sidx += 256) {
    ((float4*)o_box)[b * KEEP + sidx] = make_float4(0, 0, 0, 0);
    o_s[b * KEEP + sidx] = 0.0f;
    o_l[b * KEEP + sidx] = 0.0f;
  }
  for (int j = threadIdx.x; j < NV; j += 256) {
    const int wi = j >> 6, bi = j & 63;
    const uint64_t kword = keepw[wi];
    const int isk = (int)((kword >> bi) & 1ull);
    const uint32_t below = pref[wi] + (uint32_t)__popcll((unsigned long long)(kword & ((1ull << bi) - 1ull)));
    const uint32_t slot = isk ? below : (total + (uint32_t)j - below);
    if (slot < (uint32_t)KEEP) {
      ((float4*)o_box)[b * KEEP + slot] = *(const float4*)(topBox + ((size_t)b * PRE + j) * 4);
      o_s[b * KEEP + slot] = isk ? topS[(size_t)b * PRE + j] : 0.0f;
      o_l[b * KEEP + slot] = (float)topLab[(size_t)b * PRE + j];
    }
  }
}

extern "C" void kernel_launch(void* const* d_in, const int* in_sizes, int n_in,
                              void* d_out, int out_size, void* d_ws, size_t ws_size,
                              hipStream_t stream) {
  (void)in_sizes; (void)n_in; (void)out_size; (void)ws_size;
  const float* cls0 = (const float*)d_in[0];
  const float* cls1 = (const float*)d_in[1];
  const float* cls2 = (const float*)d_in[2];
  const float* bbox0 = (const float*)d_in[3];
  const float* bbox1 = (const float*)d_in[4];
  const float* bbox2 = (const float*)d_in[5];
  const float* obj0 = (const float*)d_in[6];
  const float* obj1 = (const float*)d_in[7];
  const float* obj2 = (const float*)d_in[8];
  const float* priors = (const float*)d_in[9];
  const float* strides = (const float*)d_in[10];
  float* out = (float*)d_out;

  char* ws = (char*)d_ws;
  size_t off = 0;
  auto alloc = [&](size_t bytes) -> void* {
    void* p = ws + off;
    off = (off + bytes + 255) & ~(size_t)255;
    return p;
  };
  uint32_t* small       = (uint32_t*)alloc(4096);
  uint32_t* flags       = small;                 // [32]
  uint32_t* cnt75       = small + 32;            // [256]
  uint32_t* candCount   = small + 288;           // [32]
  uint32_t* cutoff      = small + 320;           // [32]
  uint32_t* nvArr       = small + 352;           // [32]
  uint32_t* histDone    = small + 384;           // [32]
  uint32_t* collectDone = small + 416;           // [32]
  uint64_t* cand75    = (uint64_t*)alloc((size_t)NIMG * SUBS * SUBCAP * 8); // 4 MB
  uint32_t* hist      = (uint32_t*)alloc((size_t)NIMG * NBINS * 4);         // 2 MB (fb)
  uint64_t* cand      = (uint64_t*)alloc((size_t)NIMG * CAP * 8);           // 1 MB (fb)
  float*    topS      = (float*)alloc((size_t)NIMG * PRE * 4);
  int*      topLab    = (int*)alloc((size_t)NIMG * PRE * 4);
  float*    topBox    = (float*)alloc((size_t)NIMG * PRE * 16);
  uint64_t* maskbuf   = (uint64_t*)alloc((size_t)NIMG * PRE * 16 * 8);      // 4 MB

  hipError_t _e = hipMemsetAsync(small, 0, 4096, stream); (void)_e;

  k_pass1<<<dim3(54, NIMG), 256, 0, stream>>>(cls0, cls1, cls2, obj0, obj1, obj2,
                                              cnt75, cand75);
  k_gather<<<NIMG, 1024, 0, stream>>>(cand75, cnt75, flags, hist, bbox0, bbox1, bbox2,
                                      priors, strides, topS, topLab, topBox, nvArr);
  dim3 gScan(9, NIMG);
  k_hist_fb<<<gScan, 256, 0, stream>>>(cls0, cls1, cls2, obj0, obj1, obj2, hist, flags,
                                       histDone, cutoff);
  k_collect_fb<<<gScan, 256, 0, stream>>>(cls0, cls1, cls2, obj0, obj1, obj2,
                                          cutoff, candCount, cand, flags, collectDone,
                                          bbox0, bbox1, bbox2, priors, strides,
                                          topS, topLab, topBox, nvArr);
  k_iou<<<dim3(63, NIMG), 256, 0, stream>>>(topBox, topLab, nvArr, maskbuf);
  k_scan_out<<<NIMG, 256, 0, stream>>>(maskbuf, topS, topLab, topBox, nvArr, out);
}

// Round 17
// 359.323 us; speedup vs baseline: 2.3972x; 1.0269x over previous
//
#include <hip/hip_runtime.h>
#include <stdint.h>

#define NCLS 80
#define CELLS 8400      // 6400 + 1600 + 400
#define PRE 1000
#define KEEP 100
#define CAP 4096        // fallback candidate cap
#define NBINS 16384     // fallback histogram bins
#define NIMG 32
#define SUBS 8
#define SUBCAP 2048     // per-sub store cap (total 16384/image)
#define GBINS 4096      // gather-phase LDS histogram bins
#define COMPCAP 2048
#define T0 0.75f        // static pre-store threshold (top-1000 cutoff ~0.82 for N(0,1))
#define SCREEN 1.0886f  // logit(0.75)=1.0986 minus slack; exact test done on sigm product

typedef float nfloat4 __attribute__((ext_vector_type(4)));   // native vec for nt-load

__device__ __forceinline__ float sigm(float x) { return 1.0f / (1.0f + __expf(-x)); }

__device__ __forceinline__ void lvlinfo(int cell, int& li, int& loc, int& HW) {
  if (cell < 6400)      { li = 0; loc = cell;        HW = 6400; }
  else if (cell < 8000) { li = 1; loc = cell - 6400; HW = 1600; }
  else                  { li = 2; loc = cell - 8000; HW = 400;  }
}

// ---------------- K1: R11 mapping + NONTEMPORAL cls loads (L3 bypass) ----------------
// Grid (54, NIMG). Thread owns one float4 position and 40 channels (5 batches of 8).
// cls is 258MB streamed once per replay through a 256MB L3 (107% capacity) -> thrash:
// every line inserts+evicts, retirement capped ~1.25 TB/s across 10 structural
// variants. nt loads bypass L3 -> clean HBM stream. obj stays temporal (reused).
__global__ __launch_bounds__(256) void k_pass1(
    const float* __restrict__ cls0, const float* __restrict__ cls1, const float* __restrict__ cls2,
    const float* __restrict__ obj0, const float* __restrict__ obj1, const float* __restrict__ obj2,
    uint32_t* __restrict__ cnt75, uint64_t* __restrict__ cand75) {
  const int b = blockIdx.y;
  const int bx = blockIdx.x;
  const int sb = bx / 6;                // 9 spatial blocks
  const int r  = bx - sb * 6;
  const int h  = r & 1;                 // class half: [h*40, h*40+40)
  const int p  = r >> 1;                // prior 0..2
  const int c0cell = (sb * 256 + threadIdx.x) * 4;
  if (c0cell >= CELLS) return;
  int li, loc, HW; lvlinfo(c0cell, li, loc, HW);
  const float* cls = li == 0 ? cls0 : (li == 1 ? cls1 : cls2);
  const float* obj = li == 0 ? obj0 : (li == 1 ? obj1 : obj2);

  float4 ov = *(const float4*)(obj + ((size_t)b * 3 + p) * HW + loc);
  float os[4] = { sigm(ov.x), sigm(ov.y), sigm(ov.z), sigm(ov.w) };

  const int sub = bx & (SUBS - 1);
  const float* cp = cls + ((size_t)b * 240 + p * 80 + h * 40) * HW + loc;

  for (int gq = 0; gq < 5; ++gq) {          // 5 groups of 8 classes = 40
    nfloat4 v[8];
#pragma unroll
    for (int u = 0; u < 8; ++u)
      v[u] = __builtin_nontemporal_load((const nfloat4*)(cp + (size_t)(gq * 8 + u) * HW));
#pragma unroll
    for (int u = 0; u < 8; ++u) {
      const int c = h * 40 + gq * 8 + u;    // class within prior, 0..79
      float vv[4] = { v[u].x, v[u].y, v[u].z, v[u].w };
#pragma unroll
      for (int k = 0; k < 4; ++k) {
        if (vv[k] > SCREEN) {               // conservative logit screen (no exp for ~86%)
          float s = sigm(vv[k]) * os[k];    // exact arithmetic (same as ref path)
          if (s > T0) {
            uint32_t slot = atomicAdd(&cnt75[b * SUBS + sub], 1u);
            if (slot < SUBCAP) {
              uint32_t flat = (uint32_t)(((c0cell + k) * 3 + p) * 80 + c);
              cand75[((size_t)(b * SUBS + sub)) * SUBCAP + slot] =
                  ((uint64_t)__float_as_uint(s) << 32) | (uint64_t)(0xFFFFFFFFu - flat);
            }
          }
        }
      }
    }
  }
}

// ---------------- K3: per-image gather + exact top-1000 + decode ----------------
__global__ __launch_bounds__(1024) void k_gather(
    const uint64_t* __restrict__ cand75, const uint32_t* __restrict__ cnt75,
    uint32_t* __restrict__ flags, uint32_t* __restrict__ histg,
    const float* __restrict__ bbox0, const float* __restrict__ bbox1, const float* __restrict__ bbox2,
    const float* __restrict__ priors, const float* __restrict__ strides,
    float* __restrict__ topS, int* __restrict__ topLab, float* __restrict__ topBox,
    uint32_t* __restrict__ nvArr) {
  __shared__ uint32_t hist[GBINS];
  __shared__ uint64_t comp[COMPCAP];
  __shared__ uint32_t seg[64];
  __shared__ uint32_t ncomp_s, cb_s;
  const int b = blockIdx.x;
  const int tid = threadIdx.x;
  uint32_t tot = 0; bool bad = false;
  for (int s = 0; s < SUBS; ++s) {
    uint32_t cc = cnt75[b * SUBS + s];
    tot += cc;
    if (cc > SUBCAP) bad = true;
  }
  if (tot < (uint32_t)PRE) bad = true;
  if (bad) {
    if (tid == 0) flags[b] = 1u;
    for (int i = tid; i < NBINS; i += 1024) histg[(size_t)b * NBINS + i] = 0;
    return;
  }

  for (int i = tid; i < GBINS; i += 1024) hist[i] = 0;
  if (tid == 0) ncomp_s = 0;
  __syncthreads();
  for (int s = 0; s < SUBS; ++s) {
    uint32_t c = cnt75[b * SUBS + s];
    const uint64_t* src = cand75 + ((size_t)(b * SUBS + s)) * SUBCAP;
    for (int i = tid; i < (int)c; i += 1024) {
      uint32_t hi = (uint32_t)(src[i] >> 32);
      uint32_t bin = (hi - 0x3F400000u) >> 10;
      if (bin > GBINS - 1) bin = GBINS - 1;
      atomicAdd(&hist[bin], 1u);
    }
  }
  __syncthreads();
  if (tid < 64) {
    uint32_t s = 0;
    for (int k = 0; k < 64; ++k) s += hist[tid * 64 + k];
    seg[tid] = s;
  }
  __syncthreads();
  if (tid == 0) {
    uint32_t acc = 0; int segi = 0;
    for (int i = 63; i >= 0; --i) {
      if (acc + seg[i] >= (uint32_t)PRE) { segi = i; break; }
      acc += seg[i];
    }
    uint32_t cb = 0;
    for (int k = 63; k >= 0; --k) {
      acc += hist[segi * 64 + k];
      if (acc >= (uint32_t)PRE) { cb = (uint32_t)(segi * 64 + k); break; }
    }
    cb_s = cb;
  }
  __syncthreads();
  const uint32_t cb = cb_s;
  for (int s = 0; s < SUBS; ++s) {
    uint32_t c = cnt75[b * SUBS + s];
    const uint64_t* src = cand75 + ((size_t)(b * SUBS + s)) * SUBCAP;
    for (int i = tid; i < (int)c; i += 1024) {
      uint64_t key = src[i];
      uint32_t hi = (uint32_t)(key >> 32);
      uint32_t bin = (hi - 0x3F400000u) >> 10;
      if (bin > GBINS - 1) bin = GBINS - 1;
      if (bin >= cb) {
        uint32_t pos = atomicAdd(&ncomp_s, 1u);
        if (pos < COMPCAP) comp[pos] = key;
      }
    }
  }
  __syncthreads();
  const uint32_t ncomp = ncomp_s;
  if (ncomp > COMPCAP) {
    if (tid == 0) flags[b] = 1u;
    for (int i = tid; i < NBINS; i += 1024) histg[(size_t)b * NBINS + i] = 0;
    return;
  }
  const int N = (ncomp <= 1024u) ? 1024 : COMPCAP;   // adaptive sort size
  for (int i = tid; i < N; i += 1024) if (i >= (int)ncomp) comp[i] = 0ull;
  __syncthreads();
  for (int k = 2; k <= N; k <<= 1) {
    for (int j = k >> 1; j > 0; j >>= 1) {
      for (int i = tid; i < N; i += 1024) {
        int p = i ^ j;
        if (p > i) {
          uint64_t a = comp[i], c = comp[p];
          bool asc = (i & k) != 0;
          if (asc ? (a > c) : (a < c)) { comp[i] = c; comp[p] = a; }
        }
      }
      __syncthreads();
    }
  }
  if (tid == 0) nvArr[b] = (uint32_t)PRE;
  for (int t = tid; t < PRE; t += 1024) {
    uint64_t key = comp[t];
    float sc = __uint_as_float((uint32_t)(key >> 32));
    uint32_t flat = 0xFFFFFFFFu - (uint32_t)(key & 0xFFFFFFFFull);
    uint32_t n = flat / 80u; int lab = (int)(flat - n * 80u);
    uint32_t g = n / 3u; uint32_t p = n - g * 3u;
    int li, loc, HW; lvlinfo((int)g, li, loc, HW);
    const float* bb = li == 0 ? bbox0 : (li == 1 ? bbox1 : bbox2);
    size_t o = ((size_t)b * 12 + p * 4) * HW + loc;
    float p0 = sigm(bb[o]);
    float p1 = sigm(bb[o + (size_t)HW]);
    float p2 = sigm(bb[o + 2 * (size_t)HW]);
    float p3 = sigm(bb[o + 3 * (size_t)HW]);
    float4 pr = *(const float4*)(priors + (size_t)n * 4);
    float st = strides[n];
    float cx = (pr.x + pr.z) * 0.5f, cy = (pr.y + pr.w) * 0.5f;
    float w = pr.z - pr.x, hh = pr.w - pr.y;
    float xc = (p0 - 0.5f) * 2.0f * st + cx;
    float yc = (p1 - 0.5f) * 2.0f * st + cy;
    float wp = p2 * 2.0f; wp = wp * wp * w;
    float hp = p3 * 2.0f; hp = hp * hp * hh;
    topS[(size_t)b * PRE + t] = sc;
    topLab[(size_t)b * PRE + t] = lab;
    *(float4*)(topBox + ((size_t)b * PRE + t) * 4) =
        make_float4(xc - wp * 0.5f, yc - hp * 0.5f, xc + wp * 0.5f, yc + hp * 0.5f);
  }
}

// ================= FALLBACK PATH (per-image flag; never runs for typical data) ============
__global__ __launch_bounds__(256) void k_hist_fb(
    const float* __restrict__ cls0, const float* __restrict__ cls1, const float* __restrict__ cls2,
    const float* __restrict__ obj0, const float* __restrict__ obj1, const float* __restrict__ obj2,
    uint32_t* __restrict__ hist, const uint32_t* __restrict__ flags,
    uint32_t* __restrict__ histDone, uint32_t* __restrict__ cutoff) {
  const int b = blockIdx.y;
  if (flags[b] == 0u) return;
  __shared__ uint32_t h[NBINS];
  __shared__ uint32_t seg[256];
  __shared__ uint32_t lastArrive;
  for (int i = threadIdx.x; i < NBINS; i += 256) h[i] = 0;
  __syncthreads();
  const int c0 = (blockIdx.x * 256 + threadIdx.x) * 4;
  if (c0 < CELLS) {
    int li, loc, HW; lvlinfo(c0, li, loc, HW);
    const float* cls = li == 0 ? cls0 : (li == 1 ? cls1 : cls2);
    const float* obj = li == 0 ? obj0 : (li == 1 ? obj1 : obj2);
    float os[3][4];
#pragma unroll
    for (int p = 0; p < 3; ++p) {
      float4 o = *(const float4*)(obj + ((size_t)b * 3 + p) * HW + loc);
      os[p][0] = sigm(o.x); os[p][1] = sigm(o.y); os[p][2] = sigm(o.z); os[p][3] = sigm(o.w);
    }
    for (int p = 0; p < 3; ++p) {
      const float* cp = cls + ((size_t)b * 240 + p * 80) * HW + loc;
      for (int c = 0; c < 80; ++c) {
        float4 v = *(const float4*)(cp + (size_t)c * HW);
        float sv[4] = { sigm(v.x) * os[p][0], sigm(v.y) * os[p][1],
                        sigm(v.z) * os[p][2], sigm(v.w) * os[p][3] };
#pragma unroll
        for (int k = 0; k < 4; ++k) {
          if (sv[k] > 0.25f) {
            uint32_t key = (__float_as_uint(sv[k]) - 0x3E800000u) >> 10;
            if (key > NBINS - 1) key = NBINS - 1;
            atomicAdd(&h[key], 1u);
          }
        }
      }
    }
  }
  __syncthreads();
  for (int i = threadIdx.x; i < NBINS; i += 256) {
    uint32_t v = h[i];
    if (v) atomicAdd(&hist[(size_t)b * NBINS + i], v);
  }
  __syncthreads();
  __threadfence();
  if (threadIdx.x == 0) lastArrive = atomicAdd(&histDone[b], 1u);
  __syncthreads();
  if (lastArrive != 8) return;
  __threadfence();
  uint32_t* hb = hist + (size_t)b * NBINS;
  uint32_t s = 0;
  for (int k = 0; k < 64; ++k) s += atomicOr(&hb[threadIdx.x * 64 + k], 0u);
  seg[threadIdx.x] = s;
  __syncthreads();
  if (threadIdx.x == 0) {
    uint32_t acc = 0; int segi = -1;
    for (int i = 255; i >= 0; --i) {
      if (acc + seg[i] >= (uint32_t)PRE) { segi = i; break; }
      acc += seg[i];
    }
    uint32_t cut = 0;
    if (segi >= 0) {
      for (int k = 63; k >= 0; --k) {
        acc += atomicOr(&hb[segi * 64 + k], 0u);
        if (acc >= (uint32_t)PRE) { cut = (uint32_t)(segi * 64 + k); break; }
      }
    }
    cutoff[b] = cut;
  }
}

__global__ __launch_bounds__(256) void k_collect_fb(
    const float* __restrict__ cls0, const float* __restrict__ cls1, const float* __restrict__ cls2,
    const float* __restrict__ obj0, const float* __restrict__ obj1, const float* __restrict__ obj2,
    const uint32_t* __restrict__ cutoff, uint32_t* __restrict__ candCount,
    uint64_t* __restrict__ cand, const uint32_t* __restrict__ flags,
    uint32_t* __restrict__ collectDone,
    const float* __restrict__ bbox0, const float* __restrict__ bbox1, const float* __restrict__ bbox2,
    const float* __restrict__ priors, const float* __restrict__ strides,
    float* __restrict__ topS, int* __restrict__ topLab, float* __restrict__ topBox,
    uint32_t* __restrict__ nvArr) {
  const int b = blockIdx.y;
  if (flags[b] == 0u) return;
  __shared__ uint64_t s[CAP];
  __shared__ uint32_t lastArrive;
  const uint32_t cut = cutoff[b];
  const int c0 = (blockIdx.x * 256 + threadIdx.x) * 4;
  if (c0 < CELLS) {
    int li, loc, HW; lvlinfo(c0, li, loc, HW);
    const float* cls = li == 0 ? cls0 : (li == 1 ? cls1 : cls2);
    const float* obj = li == 0 ? obj0 : (li == 1 ? obj1 : obj2);
    float os[3][4];
#pragma unroll
    for (int p = 0; p < 3; ++p) {
      float4 o = *(const float4*)(obj + ((size_t)b * 3 + p) * HW + loc);
      os[p][0] = sigm(o.x); os[p][1] = sigm(o.y); os[p][2] = sigm(o.z); os[p][3] = sigm(o.w);
    }
    for (int p = 0; p < 3; ++p) {
      const float* cp = cls + ((size_t)b * 240 + p * 80) * HW + loc;
      for (int c = 0; c < 80; ++c) {
        float4 v = *(const float4*)(cp + (size_t)c * HW);
        float sv[4] = { sigm(v.x) * os[p][0], sigm(v.y) * os[p][1],
                        sigm(v.z) * os[p][2], sigm(v.w) * os[p][3] };
#pragma unroll
        for (int k = 0; k < 4; ++k) {
          float sk = sv[k];
          if (sk > 0.25f) {
            uint32_t key = (__float_as_uint(sk) - 0x3E800000u) >> 10;
            if (key >= cut) {
              uint32_t pos = atomicAdd(&candCount[b], 1u);
              if (pos < CAP) {
                uint32_t flat = (uint32_t)((((c0 + k) * 3 + p) * 80) + c);
                cand[(size_t)b * CAP + pos] =
                    ((uint64_t)__float_as_uint(sk) << 32) | (uint64_t)(0xFFFFFFFFu - flat);
              }
            }
          }
        }
      }
    }
  }
  __syncthreads();
  __threadfence();
  if (threadIdx.x == 0) lastArrive = atomicAdd(&collectDone[b], 1u);
  __syncthreads();
  if (lastArrive != 8) return;
  __threadfence();
  uint32_t cnt = atomicOr(&candCount[b], 0u); if (cnt > (uint32_t)CAP) cnt = CAP;
  for (int i = threadIdx.x; i < CAP; i += 256)
    s[i] = (i < (int)cnt) ? cand[(size_t)b * CAP + i] : 0ull;
  __syncthreads();
  for (int k = 2; k <= CAP; k <<= 1) {
    for (int j = k >> 1; j > 0; j >>= 1) {
      for (int i = threadIdx.x; i < CAP; i += 256) {
        int p = i ^ j;
        if (p > i) {
          uint64_t a = s[i], c = s[p];
          bool asc = (i & k) != 0;
          if (asc ? (a > c) : (a < c)) { s[i] = c; s[p] = a; }
        }
      }
      __syncthreads();
    }
  }
  const int NV = (int)(cnt < (uint32_t)PRE ? cnt : (uint32_t)PRE);
  if (threadIdx.x == 0) nvArr[b] = (uint32_t)NV;
  for (int t = threadIdx.x; t < PRE; t += 256) {
    float sc = 0.0f; int lab = 0; float b0 = 0, b1 = 0, b2v = 0, b3 = 0;
    if (t < NV) {
      uint64_t key = s[t];
      sc = __uint_as_float((uint32_t)(key >> 32));
      uint32_t flat = 0xFFFFFFFFu - (uint32_t)(key & 0xFFFFFFFFull);
      uint32_t n = flat / 80u; lab = (int)(flat - n * 80u);
      uint32_t g = n / 3u; uint32_t p = n - g * 3u;
      int li, loc, HW; lvlinfo((int)g, li, loc, HW);
      const float* bb = li == 0 ? bbox0 : (li == 1 ? bbox1 : bbox2);
      size_t o = ((size_t)b * 12 + p * 4) * HW + loc;
      float p0 = sigm(bb[o]);
      float p1 = sigm(bb[o + (size_t)HW]);
      float p2 = sigm(bb[o + 2 * (size_t)HW]);
      float p3 = sigm(bb[o + 3 * (size_t)HW]);
      float4 pr = *(const float4*)(priors + (size_t)n * 4);
      float st = strides[n];
      float cx = (pr.x + pr.z) * 0.5f, cy = (pr.y + pr.w) * 0.5f;
      float w = pr.z - pr.x, hh = pr.w - pr.y;
      float xc = (p0 - 0.5f) * 2.0f * st + cx;
      float yc = (p1 - 0.5f) * 2.0f * st + cy;
      float wp = p2 * 2.0f; wp = wp * wp * w;
      float hp = p3 * 2.0f; hp = hp * hp * hh;
      b0 = xc - wp * 0.5f; b1 = yc - hp * 0.5f; b2v = xc + wp * 0.5f; b3 = yc + hp * 0.5f;
    }
    topS[(size_t)b * PRE + t] = sc;
    topLab[(size_t)b * PRE + t] = lab;
    *(float4*)(topBox + ((size_t)b * PRE + t) * 4) = make_float4(b0, b1, b2v, b3);
  }
}

// ---------------- K5: IoU suppression bitmask (63 blocks/image) ----------------
__global__ __launch_bounds__(256) void k_iou(
    const float* __restrict__ topBox, const int* __restrict__ topLab,
    const uint32_t* __restrict__ nvArr, uint64_t* __restrict__ mask) {
  __shared__ float4 bx[PRE];
  __shared__ int lb[PRE];
  const int b = blockIdx.y;
  const int NV = (int)nvArr[b];
  for (int i = threadIdx.x; i < PRE; i += 256) {
    bx[i] = *(const float4*)(topBox + ((size_t)b * PRE + i) * 4);
    lb[i] = topLab[(size_t)b * PRE + i];
  }
  __syncthreads();
  for (int task = blockIdx.x * 256 + threadIdx.x; task < PRE * 16; task += gridDim.x * 256) {
    const int i = task >> 4, w = task & 15;
    uint64_t m = 0;
    if (i < NV) {
      const float4 a = bx[i]; const int la = lb[i];
      const float areaA = (a.z - a.x) * (a.w - a.y);
      const int j0 = w << 6;
      const int jend = (j0 + 64 < NV) ? j0 + 64 : NV;
      for (int j = (j0 > i + 1 ? j0 : i + 1); j < jend; ++j) {
        if (lb[j] != la) continue;
        const float4 c = bx[j];
        float xx1 = fmaxf(a.x, c.x), yy1 = fmaxf(a.y, c.y);
        float xx2 = fminf(a.z, c.z), yy2 = fminf(a.w, c.w);
        float iw = fmaxf(xx2 - xx1, 0.0f), ih = fmaxf(yy2 - yy1, 0.0f);
        float inter = iw * ih;
        float areaB = (c.z - c.x) * (c.w - c.y);
        float iou = inter / (areaA + areaB - inter + 1e-7f);
        if (iou > 0.65f) m |= (1ull << (j - j0));
      }
    }
    mask[((size_t)b * PRE + i) * 16 + w] = m;
  }
}

// ---------------- K6: serial greedy scan (branchless, pipelined) + output assembly --------
__global__ __launch_bounds__(256) void k_scan_out(
    const uint64_t* __restrict__ mask, const float* __restrict__ topS,
    const int* __restrict__ topLab, const float* __restrict__ topBox,
    const uint32_t* __restrict__ nvArr, float* __restrict__ out) {
  __shared__ uint64_t rows[PRE * 16];   // 125 KB
  __shared__ uint64_t keepw[16];
  __shared__ uint32_t pref[17];
  const int b = blockIdx.x;
  const int NV = (int)nvArr[b];
  for (int i = threadIdx.x; i < NV * 16; i += 256) rows[i] = mask[(size_t)b * PRE * 16 + i];
  __syncthreads();
  if (threadIdx.x < 64) {
    const int lane = threadIdx.x;
    uint64_t remv = 0, kw = 0;
    for (int w0 = 0; w0 * 64 < NV; ++w0) {
      uint64_t cur = (uint64_t)__shfl((unsigned long long)remv, w0);
      const int ie = (w0 * 64 + 64 < NV) ? w0 * 64 + 64 : NV;
      for (int i = w0 * 64; i < ie; ++i) {
        const int bi = i & 63;
        uint64_t rl = rows[i * 16 + (lane & 15)];
        uint64_t cw = rows[i * 16 + w0];
        const uint64_t keepm = ((cur >> bi) & 1ull) ? 0ull : ~0ull;
        cur |= cw & keepm;
        remv |= rl & keepm;
        kw |= (lane == w0) ? ((1ull << bi) & keepm) : 0ull;
      }
    }
    if (lane < 16) keepw[lane] = kw;
  }
  __syncthreads();
  if (threadIdx.x == 0) {
    uint32_t a = 0;
    for (int w = 0; w < 16; ++w) { pref[w] = a; a += (uint32_t)__popcll((unsigned long long)keepw[w]); }
    pref[16] = a;
  }
  __syncthreads();
  const uint32_t total = pref[16];
  const uint32_t num = total < (uint32_t)KEEP ? total : (uint32_t)KEEP;
  float* o_num = out;
  float* o_box = out + NIMG;
  float* o_s   = out + NIMG + NIMG * KEEP * 4;
  float* o_l   = o_s + NIMG * KEEP;
  if (threadIdx.x == 0) o_num[b] = (float)num;
  const int zstart = NV < KEEP ? NV : KEEP;
  for (int sidx = zstart + threadIdx.x; sidx < KEEP; sidx += 256) {
    ((float4*)o_box)[b * KEEP + sidx] = make_float4(0, 0, 0, 0);
    o_s[b * KEEP + sidx] = 0.0f;
    o_l[b * KEEP + sidx] = 0.0f;
  }
  for (int j = threadIdx.x; j < NV; j += 256) {
    const int wi = j >> 6, bi = j & 63;
    const uint64_t kword = keepw[wi];
    const int isk = (int)((kword >> bi) & 1ull);
    const uint32_t below = pref[wi] + (uint32_t)__popcll((unsigned long long)(kword & ((1ull << bi) - 1ull)));
    const uint32_t slot = isk ? below : (total + (uint32_t)j - below);
    if (slot < (uint32_t)KEEP) {
      ((float4*)o_box)[b * KEEP + slot] = *(const float4*)(topBox + ((size_t)b * PRE + j) * 4);
      o_s[b * KEEP + slot] = isk ? topS[(size_t)b * PRE + j] : 0.0f;
      o_l[b * KEEP + slot] = (float)topLab[(size_t)b * PRE + j];
    }
  }
}

extern "C" void kernel_launch(void* const* d_in, const int* in_sizes, int n_in,
                              void* d_out, int out_size, void* d_ws, size_t ws_size,
                              hipStream_t stream) {
  (void)in_sizes; (void)n_in; (void)out_size; (void)ws_size;
  const float* cls0 = (const float*)d_in[0];
  const float* cls1 = (const float*)d_in[1];
  const float* cls2 = (const float*)d_in[2];
  const float* bbox0 = (const float*)d_in[3];
  const float* bbox1 = (const float*)d_in[4];
  const float* bbox2 = (const float*)d_in[5];
  const float* obj0 = (const float*)d_in[6];
  const float* obj1 = (const float*)d_in[7];
  const float* obj2 = (const float*)d_in[8];
  const float* priors = (const float*)d_in[9];
  const float* strides = (const float*)d_in[10];
  float* out = (float*)d_out;

  char* ws = (char*)d_ws;
  size_t off = 0;
  auto alloc = [&](size_t bytes) -> void* {
    void* p = ws + off;
    off = (off + bytes + 255) & ~(size_t)255;
    return p;
  };
  uint32_t* small       = (uint32_t*)alloc(4096);
  uint32_t* flags       = small;                 // [32]
  uint32_t* cnt75       = small + 32;            // [256]
  uint32_t* candCount   = small + 288;           // [32]
  uint32_t* cutoff      = small + 320;           // [32]
  uint32_t* nvArr       = small + 352;           // [32]
  uint32_t* histDone    = small + 384;           // [32]
  uint32_t* collectDone = small + 416;           // [32]
  uint64_t* cand75    = (uint64_t*)alloc((size_t)NIMG * SUBS * SUBCAP * 8); // 4 MB
  uint32_t* hist      = (uint32_t*)alloc((size_t)NIMG * NBINS * 4);         // 2 MB (fb)
  uint64_t* cand      = (uint64_t*)alloc((size_t)NIMG * CAP * 8);           // 1 MB (fb)
  float*    topS      = (float*)alloc((size_t)NIMG * PRE * 4);
  int*      topLab    = (int*)alloc((size_t)NIMG * PRE * 4);
  float*    topBox    = (float*)alloc((size_t)NIMG * PRE * 16);
  uint64_t* maskbuf   = (uint64_t*)alloc((size_t)NIMG * PRE * 16 * 8);      // 4 MB

  hipError_t _e = hipMemsetAsync(small, 0, 4096, stream); (void)_e;

  k_pass1<<<dim3(54, NIMG), 256, 0, stream>>>(cls0, cls1, cls2, obj0, obj1, obj2,
                                              cnt75, cand75);
  k_gather<<<NIMG, 1024, 0, stream>>>(cand75, cnt75, flags, hist, bbox0, bbox1, bbox2,
                                      priors, strides, topS, topLab, topBox, nvArr);
  dim3 gScan(9, NIMG);
  k_hist_fb<<<gScan, 256, 0, stream>>>(cls0, cls1, cls2, obj0, obj1, obj2, hist, flags,
                                       histDone, cutoff);
  k_collect_fb<<<gScan, 256, 0, stream>>>(cls0, cls1, cls2, obj0, obj1, obj2,
                                          cutoff, candCount, cand, flags, collectDone,
                                          bbox0, bbox1, bbox2, priors, strides,
                                          topS, topLab, topBox, nvArr);
  k_iou<<<dim3(63, NIMG), 256, 0, stream>>>(topBox, topLab, nvArr, maskbuf);
  k_scan_out<<<NIMG, 256, 0, stream>>>(maskbuf, topS, topLab, topBox, nvArr, out);
}

// Round 18
// 346.257 us; speedup vs baseline: 2.4877x; 1.0377x over previous
//
#include <hip/hip_runtime.h>
#include <stdint.h>

#define NCLS 80
#define CELLS 8400      // 6400 + 1600 + 400
#define PRE 1000
#define KEEP 100
#define CAP 4096        // fallback candidate cap
#define NBINS 16384     // fallback histogram bins
#define NIMG 32
#define SUBS 8
#define SUBCAP 2048     // per-sub store cap (total 16384/image)
#define GBINS 4096      // gather-phase LDS histogram bins
#define COMPCAP 2048
#define T0 0.75f        // static pre-store threshold (top-1000 cutoff ~0.82 for N(0,1))
#define SCREEN 1.0886f  // logit(0.75)=1.0986 minus slack; exact test done on sigm product

typedef float nfloat4 __attribute__((ext_vector_type(4)));   // native vec for nt-load

__device__ __forceinline__ float sigm(float x) { return 1.0f / (1.0f + __expf(-x)); }

__device__ __forceinline__ void lvlinfo(int cell, int& li, int& loc, int& HW) {
  if (cell < 6400)      { li = 0; loc = cell;        HW = 6400; }
  else if (cell < 8000) { li = 1; loc = cell - 6400; HW = 1600; }
  else                  { li = 2; loc = cell - 8000; HW = 400;  }
}

// ---------------- K1: R17 pass1 (empirical plateau ~205us; 11-variant sweep closed) -------
__global__ __launch_bounds__(256) void k_pass1(
    const float* __restrict__ cls0, const float* __restrict__ cls1, const float* __restrict__ cls2,
    const float* __restrict__ obj0, const float* __restrict__ obj1, const float* __restrict__ obj2,
    uint32_t* __restrict__ cnt75, uint64_t* __restrict__ cand75) {
  const int b = blockIdx.y;
  const int bx = blockIdx.x;
  const int sb = bx / 6;                // 9 spatial blocks
  const int r  = bx - sb * 6;
  const int h  = r & 1;                 // class half: [h*40, h*40+40)
  const int p  = r >> 1;                // prior 0..2
  const int c0cell = (sb * 256 + threadIdx.x) * 4;
  if (c0cell >= CELLS) return;
  int li, loc, HW; lvlinfo(c0cell, li, loc, HW);
  const float* cls = li == 0 ? cls0 : (li == 1 ? cls1 : cls2);
  const float* obj = li == 0 ? obj0 : (li == 1 ? obj1 : obj2);

  float4 ov = *(const float4*)(obj + ((size_t)b * 3 + p) * HW + loc);
  float os[4] = { sigm(ov.x), sigm(ov.y), sigm(ov.z), sigm(ov.w) };

  const int sub = bx & (SUBS - 1);
  const float* cp = cls + ((size_t)b * 240 + p * 80 + h * 40) * HW + loc;

  for (int gq = 0; gq < 5; ++gq) {          // 5 groups of 8 classes = 40
    nfloat4 v[8];
#pragma unroll
    for (int u = 0; u < 8; ++u)
      v[u] = __builtin_nontemporal_load((const nfloat4*)(cp + (size_t)(gq * 8 + u) * HW));
#pragma unroll
    for (int u = 0; u < 8; ++u) {
      const int c = h * 40 + gq * 8 + u;    // class within prior, 0..79
      float vv[4] = { v[u].x, v[u].y, v[u].z, v[u].w };
#pragma unroll
      for (int k = 0; k < 4; ++k) {
        if (vv[k] > SCREEN) {               // conservative logit screen (no exp for ~86%)
          float s = sigm(vv[k]) * os[k];    // exact arithmetic (same as ref path)
          if (s > T0) {
            uint32_t slot = atomicAdd(&cnt75[b * SUBS + sub], 1u);
            if (slot < SUBCAP) {
              uint32_t flat = (uint32_t)(((c0cell + k) * 3 + p) * 80 + c);
              cand75[((size_t)(b * SUBS + sub)) * SUBCAP + slot] =
                  ((uint64_t)__float_as_uint(s) << 32) | (uint64_t)(0xFFFFFFFFu - flat);
            }
          }
        }
      }
    }
  }
}

// ---------------- K3: per-image gather + exact top-1000 + decode ----------------
__global__ __launch_bounds__(1024) void k_gather(
    const uint64_t* __restrict__ cand75, const uint32_t* __restrict__ cnt75,
    uint32_t* __restrict__ flags, uint32_t* __restrict__ histg,
    const float* __restrict__ bbox0, const float* __restrict__ bbox1, const float* __restrict__ bbox2,
    const float* __restrict__ priors, const float* __restrict__ strides,
    float* __restrict__ topS, int* __restrict__ topLab, float* __restrict__ topBox,
    uint32_t* __restrict__ nvArr) {
  __shared__ uint32_t hist[GBINS];
  __shared__ uint64_t comp[COMPCAP];
  __shared__ uint32_t seg[64];
  __shared__ uint32_t ncomp_s, cb_s;
  const int b = blockIdx.x;
  const int tid = threadIdx.x;
  uint32_t tot = 0; bool bad = false;
  for (int s = 0; s < SUBS; ++s) {
    uint32_t cc = cnt75[b * SUBS + s];
    tot += cc;
    if (cc > SUBCAP) bad = true;
  }
  if (tot < (uint32_t)PRE) bad = true;
  if (bad) {
    if (tid == 0) flags[b] = 1u;
    for (int i = tid; i < NBINS; i += 1024) histg[(size_t)b * NBINS + i] = 0;
    return;
  }

  for (int i = tid; i < GBINS; i += 1024) hist[i] = 0;
  if (tid == 0) ncomp_s = 0;
  __syncthreads();
  for (int s = 0; s < SUBS; ++s) {
    uint32_t c = cnt75[b * SUBS + s];
    const uint64_t* src = cand75 + ((size_t)(b * SUBS + s)) * SUBCAP;
    for (int i = tid; i < (int)c; i += 1024) {
      uint32_t hi = (uint32_t)(src[i] >> 32);
      uint32_t bin = (hi - 0x3F400000u) >> 10;
      if (bin > GBINS - 1) bin = GBINS - 1;
      atomicAdd(&hist[bin], 1u);
    }
  }
  __syncthreads();
  if (tid < 64) {
    uint32_t s = 0;
    for (int k = 0; k < 64; ++k) s += hist[tid * 64 + k];
    seg[tid] = s;
  }
  __syncthreads();
  if (tid == 0) {
    uint32_t acc = 0; int segi = 0;
    for (int i = 63; i >= 0; --i) {
      if (acc + seg[i] >= (uint32_t)PRE) { segi = i; break; }
      acc += seg[i];
    }
    uint32_t cb = 0;
    for (int k = 63; k >= 0; --k) {
      acc += hist[segi * 64 + k];
      if (acc >= (uint32_t)PRE) { cb = (uint32_t)(segi * 64 + k); break; }
    }
    cb_s = cb;
  }
  __syncthreads();
  const uint32_t cb = cb_s;
  for (int s = 0; s < SUBS; ++s) {
    uint32_t c = cnt75[b * SUBS + s];
    const uint64_t* src = cand75 + ((size_t)(b * SUBS + s)) * SUBCAP;
    for (int i = tid; i < (int)c; i += 1024) {
      uint64_t key = src[i];
      uint32_t hi = (uint32_t)(key >> 32);
      uint32_t bin = (hi - 0x3F400000u) >> 10;
      if (bin > GBINS - 1) bin = GBINS - 1;
      if (bin >= cb) {
        uint32_t pos = atomicAdd(&ncomp_s, 1u);
        if (pos < COMPCAP) comp[pos] = key;
      }
    }
  }
  __syncthreads();
  const uint32_t ncomp = ncomp_s;
  if (ncomp > COMPCAP) {
    if (tid == 0) flags[b] = 1u;
    for (int i = tid; i < NBINS; i += 1024) histg[(size_t)b * NBINS + i] = 0;
    return;
  }
  const int N = (ncomp <= 1024u) ? 1024 : COMPCAP;   // adaptive sort size
  for (int i = tid; i < N; i += 1024) if (i >= (int)ncomp) comp[i] = 0ull;
  __syncthreads();
  for (int k = 2; k <= N; k <<= 1) {
    for (int j = k >> 1; j > 0; j >>= 1) {
      for (int i = tid; i < N; i += 1024) {
        int p = i ^ j;
        if (p > i) {
          uint64_t a = comp[i], c = comp[p];
          bool asc = (i & k) != 0;
          if (asc ? (a > c) : (a < c)) { comp[i] = c; comp[p] = a; }
        }
      }
      __syncthreads();
    }
  }
  if (tid == 0) nvArr[b] = (uint32_t)PRE;
  for (int t = tid; t < PRE; t += 1024) {
    uint64_t key = comp[t];
    float sc = __uint_as_float((uint32_t)(key >> 32));
    uint32_t flat = 0xFFFFFFFFu - (uint32_t)(key & 0xFFFFFFFFull);
    uint32_t n = flat / 80u; int lab = (int)(flat - n * 80u);
    uint32_t g = n / 3u; uint32_t p = n - g * 3u;
    int li, loc, HW; lvlinfo((int)g, li, loc, HW);
    const float* bb = li == 0 ? bbox0 : (li == 1 ? bbox1 : bbox2);
    size_t o = ((size_t)b * 12 + p * 4) * HW + loc;
    float p0 = sigm(bb[o]);
    float p1 = sigm(bb[o + (size_t)HW]);
    float p2 = sigm(bb[o + 2 * (size_t)HW]);
    float p3 = sigm(bb[o + 3 * (size_t)HW]);
    float4 pr = *(const float4*)(priors + (size_t)n * 4);
    float st = strides[n];
    float cx = (pr.x + pr.z) * 0.5f, cy = (pr.y + pr.w) * 0.5f;
    float w = pr.z - pr.x, hh = pr.w - pr.y;
    float xc = (p0 - 0.5f) * 2.0f * st + cx;
    float yc = (p1 - 0.5f) * 2.0f * st + cy;
    float wp = p2 * 2.0f; wp = wp * wp * w;
    float hp = p3 * 2.0f; hp = hp * hp * hh;
    topS[(size_t)b * PRE + t] = sc;
    topLab[(size_t)b * PRE + t] = lab;
    *(float4*)(topBox + ((size_t)b * PRE + t) * 4) =
        make_float4(xc - wp * 0.5f, yc - hp * 0.5f, xc + wp * 0.5f, yc + hp * 0.5f);
  }
}

// ================= FALLBACK PATH (per-image flag; never runs for typical data) ============
__global__ __launch_bounds__(256) void k_hist_fb(
    const float* __restrict__ cls0, const float* __restrict__ cls1, const float* __restrict__ cls2,
    const float* __restrict__ obj0, const float* __restrict__ obj1, const float* __restrict__ obj2,
    uint32_t* __restrict__ hist, const uint32_t* __restrict__ flags,
    uint32_t* __restrict__ histDone, uint32_t* __restrict__ cutoff) {
  const int b = blockIdx.y;
  if (flags[b] == 0u) return;
  __shared__ uint32_t h[NBINS];
  __shared__ uint32_t seg[256];
  __shared__ uint32_t lastArrive;
  for (int i = threadIdx.x; i < NBINS; i += 256) h[i] = 0;
  __syncthreads();
  const int c0 = (blockIdx.x * 256 + threadIdx.x) * 4;
  if (c0 < CELLS) {
    int li, loc, HW; lvlinfo(c0, li, loc, HW);
    const float* cls = li == 0 ? cls0 : (li == 1 ? cls1 : cls2);
    const float* obj = li == 0 ? obj0 : (li == 1 ? obj1 : obj2);
    float os[3][4];
#pragma unroll
    for (int p = 0; p < 3; ++p) {
      float4 o = *(const float4*)(obj + ((size_t)b * 3 + p) * HW + loc);
      os[p][0] = sigm(o.x); os[p][1] = sigm(o.y); os[p][2] = sigm(o.z); os[p][3] = sigm(o.w);
    }
    for (int p = 0; p < 3; ++p) {
      const float* cp = cls + ((size_t)b * 240 + p * 80) * HW + loc;
      for (int c = 0; c < 80; ++c) {
        float4 v = *(const float4*)(cp + (size_t)c * HW);
        float sv[4] = { sigm(v.x) * os[p][0], sigm(v.y) * os[p][1],
                        sigm(v.z) * os[p][2], sigm(v.w) * os[p][3] };
#pragma unroll
        for (int k = 0; k < 4; ++k) {
          if (sv[k] > 0.25f) {
            uint32_t key = (__float_as_uint(sv[k]) - 0x3E800000u) >> 10;
            if (key > NBINS - 1) key = NBINS - 1;
            atomicAdd(&h[key], 1u);
          }
        }
      }
    }
  }
  __syncthreads();
  for (int i = threadIdx.x; i < NBINS; i += 256) {
    uint32_t v = h[i];
    if (v) atomicAdd(&hist[(size_t)b * NBINS + i], v);
  }
  __syncthreads();
  __threadfence();
  if (threadIdx.x == 0) lastArrive = atomicAdd(&histDone[b], 1u);
  __syncthreads();
  if (lastArrive != 8) return;
  __threadfence();
  uint32_t* hb = hist + (size_t)b * NBINS;
  uint32_t s = 0;
  for (int k = 0; k < 64; ++k) s += atomicOr(&hb[threadIdx.x * 64 + k], 0u);
  seg[threadIdx.x] = s;
  __syncthreads();
  if (threadIdx.x == 0) {
    uint32_t acc = 0; int segi = -1;
    for (int i = 255; i >= 0; --i) {
      if (acc + seg[i] >= (uint32_t)PRE) { segi = i; break; }
      acc += seg[i];
    }
    uint32_t cut = 0;
    if (segi >= 0) {
      for (int k = 63; k >= 0; --k) {
        acc += atomicOr(&hb[segi * 64 + k], 0u);
        if (acc >= (uint32_t)PRE) { cut = (uint32_t)(segi * 64 + k); break; }
      }
    }
    cutoff[b] = cut;
  }
}

__global__ __launch_bounds__(256) void k_collect_fb(
    const float* __restrict__ cls0, const float* __restrict__ cls1, const float* __restrict__ cls2,
    const float* __restrict__ obj0, const float* __restrict__ obj1, const float* __restrict__ obj2,
    const uint32_t* __restrict__ cutoff, uint32_t* __restrict__ candCount,
    uint64_t* __restrict__ cand, const uint32_t* __restrict__ flags,
    uint32_t* __restrict__ collectDone,
    const float* __restrict__ bbox0, const float* __restrict__ bbox1, const float* __restrict__ bbox2,
    const float* __restrict__ priors, const float* __restrict__ strides,
    float* __restrict__ topS, int* __restrict__ topLab, float* __restrict__ topBox,
    uint32_t* __restrict__ nvArr) {
  const int b = blockIdx.y;
  if (flags[b] == 0u) return;
  __shared__ uint64_t s[CAP];
  __shared__ uint32_t lastArrive;
  const uint32_t cut = cutoff[b];
  const int c0 = (blockIdx.x * 256 + threadIdx.x) * 4;
  if (c0 < CELLS) {
    int li, loc, HW; lvlinfo(c0, li, loc, HW);
    const float* cls = li == 0 ? cls0 : (li == 1 ? cls1 : cls2);
    const float* obj = li == 0 ? obj0 : (li == 1 ? obj1 : obj2);
    float os[3][4];
#pragma unroll
    for (int p = 0; p < 3; ++p) {
      float4 o = *(const float4*)(obj + ((size_t)b * 3 + p) * HW + loc);
      os[p][0] = sigm(o.x); os[p][1] = sigm(o.y); os[p][2] = sigm(o.z); os[p][3] = sigm(o.w);
    }
    for (int p = 0; p < 3; ++p) {
      const float* cp = cls + ((size_t)b * 240 + p * 80) * HW + loc;
      for (int c = 0; c < 80; ++c) {
        float4 v = *(const float4*)(cp + (size_t)c * HW);
        float sv[4] = { sigm(v.x) * os[p][0], sigm(v.y) * os[p][1],
                        sigm(v.z) * os[p][2], sigm(v.w) * os[p][3] };
#pragma unroll
        for (int k = 0; k < 4; ++k) {
          float sk = sv[k];
          if (sk > 0.25f) {
            uint32_t key = (__float_as_uint(sk) - 0x3E800000u) >> 10;
            if (key >= cut) {
              uint32_t pos = atomicAdd(&candCount[b], 1u);
              if (pos < CAP) {
                uint32_t flat = (uint32_t)((((c0 + k) * 3 + p) * 80) + c);
                cand[(size_t)b * CAP + pos] =
                    ((uint64_t)__float_as_uint(sk) << 32) | (uint64_t)(0xFFFFFFFFu - flat);
              }
            }
          }
        }
      }
    }
  }
  __syncthreads();
  __threadfence();
  if (threadIdx.x == 0) lastArrive = atomicAdd(&collectDone[b], 1u);
  __syncthreads();
  if (lastArrive != 8) return;
  __threadfence();
  uint32_t cnt = atomicOr(&candCount[b], 0u); if (cnt > (uint32_t)CAP) cnt = CAP;
  for (int i = threadIdx.x; i < CAP; i += 256)
    s[i] = (i < (int)cnt) ? cand[(size_t)b * CAP + i] : 0ull;
  __syncthreads();
  for (int k = 2; k <= CAP; k <<= 1) {
    for (int j = k >> 1; j > 0; j >>= 1) {
      for (int i = threadIdx.x; i < CAP; i += 256) {
        int p = i ^ j;
        if (p > i) {
          uint64_t a = s[i], c = s[p];
          bool asc = (i & k) != 0;
          if (asc ? (a > c) : (a < c)) { s[i] = c; s[p] = a; }
        }
      }
      __syncthreads();
    }
  }
  const int NV = (int)(cnt < (uint32_t)PRE ? cnt : (uint32_t)PRE);
  if (threadIdx.x == 0) nvArr[b] = (uint32_t)NV;
  for (int t = threadIdx.x; t < PRE; t += 256) {
    float sc = 0.0f; int lab = 0; float b0 = 0, b1 = 0, b2v = 0, b3 = 0;
    if (t < NV) {
      uint64_t key = s[t];
      sc = __uint_as_float((uint32_t)(key >> 32));
      uint32_t flat = 0xFFFFFFFFu - (uint32_t)(key & 0xFFFFFFFFull);
      uint32_t n = flat / 80u; lab = (int)(flat - n * 80u);
      uint32_t g = n / 3u; uint32_t p = n - g * 3u;
      int li, loc, HW; lvlinfo((int)g, li, loc, HW);
      const float* bb = li == 0 ? bbox0 : (li == 1 ? bbox1 : bbox2);
      size_t o = ((size_t)b * 12 + p * 4) * HW + loc;
      float p0 = sigm(bb[o]);
      float p1 = sigm(bb[o + (size_t)HW]);
      float p2 = sigm(bb[o + 2 * (size_t)HW]);
      float p3 = sigm(bb[o + 3 * (size_t)HW]);
      float4 pr = *(const float4*)(priors + (size_t)n * 4);
      float st = strides[n];
      float cx = (pr.x + pr.z) * 0.5f, cy = (pr.y + pr.w) * 0.5f;
      float w = pr.z - pr.x, hh = pr.w - pr.y;
      float xc = (p0 - 0.5f) * 2.0f * st + cx;
      float yc = (p1 - 0.5f) * 2.0f * st + cy;
      float wp = p2 * 2.0f; wp = wp * wp * w;
      float hp = p3 * 2.0f; hp = hp * hp * hh;
      b0 = xc - wp * 0.5f; b1 = yc - hp * 0.5f; b2v = xc + wp * 0.5f; b3 = yc + hp * 0.5f;
    }
    topS[(size_t)b * PRE + t] = sc;
    topLab[(size_t)b * PRE + t] = lab;
    *(float4*)(topBox + ((size_t)b * PRE + t) * 4) = make_float4(b0, b1, b2v, b3);
  }
}

// ---------------- K5: IoU suppression bitmask (63 blocks/image) ----------------
__global__ __launch_bounds__(256) void k_iou(
    const float* __restrict__ topBox, const int* __restrict__ topLab,
    const uint32_t* __restrict__ nvArr, uint64_t* __restrict__ mask) {
  __shared__ float4 bx[PRE];
  __shared__ int lb[PRE];
  const int b = blockIdx.y;
  const int NV = (int)nvArr[b];
  for (int i = threadIdx.x; i < PRE; i += 256) {
    bx[i] = *(const float4*)(topBox + ((size_t)b * PRE + i) * 4);
    lb[i] = topLab[(size_t)b * PRE + i];
  }
  __syncthreads();
  for (int task = blockIdx.x * 256 + threadIdx.x; task < PRE * 16; task += gridDim.x * 256) {
    const int i = task >> 4, w = task & 15;
    uint64_t m = 0;
    if (i < NV) {
      const float4 a = bx[i]; const int la = lb[i];
      const float areaA = (a.z - a.x) * (a.w - a.y);
      const int j0 = w << 6;
      const int jend = (j0 + 64 < NV) ? j0 + 64 : NV;
      for (int j = (j0 > i + 1 ? j0 : i + 1); j < jend; ++j) {
        if (lb[j] != la) continue;
        const float4 c = bx[j];
        float xx1 = fmaxf(a.x, c.x), yy1 = fmaxf(a.y, c.y);
        float xx2 = fminf(a.z, c.z), yy2 = fminf(a.w, c.w);
        float iw = fmaxf(xx2 - xx1, 0.0f), ih = fmaxf(yy2 - yy1, 0.0f);
        float inter = iw * ih;
        float areaB = (c.z - c.x) * (c.w - c.y);
        float iou = inter / (areaA + areaB - inter + 1e-7f);
        if (iou > 0.65f) m |= (1ull << (j - j0));
      }
    }
    mask[((size_t)b * PRE + i) * 16 + w] = m;
  }
}

// ---------------- K6: greedy scan with unroll-4 LDS prefetch + output assembly ------------
// The cur-chain is serial, but row addresses are independent of cur: load 8 rows/chunk
// into registers FIRST, then run 4 pure-VALU dependency steps -> LDS latency amortized
// over chunks instead of paid per iteration.
__global__ __launch_bounds__(256) void k_scan_out(
    const uint64_t* __restrict__ mask, const float* __restrict__ topS,
    const int* __restrict__ topLab, const float* __restrict__ topBox,
    const uint32_t* __restrict__ nvArr, float* __restrict__ out) {
  __shared__ uint64_t rows[PRE * 16];   // 125 KB
  __shared__ uint64_t keepw[16];
  __shared__ uint32_t pref[17];
  const int b = blockIdx.x;
  const int NV = (int)nvArr[b];
  for (int i = threadIdx.x; i < NV * 16; i += 256) rows[i] = mask[(size_t)b * PRE * 16 + i];
  __syncthreads();
  if (threadIdx.x < 64) {
    const int lane = threadIdx.x;
    uint64_t remv = 0, kw = 0;
    for (int w0 = 0; w0 * 64 < NV; ++w0) {
      uint64_t cur = (uint64_t)__shfl((unsigned long long)remv, w0);
      const int ie = (w0 * 64 + 64 < NV) ? w0 * 64 + 64 : NV;
      int i = w0 * 64;
      for (; i + 4 <= ie; i += 4) {
        uint64_t rl[4], cw[4];
#pragma unroll
        for (int t = 0; t < 4; ++t) {
          rl[t] = rows[(i + t) * 16 + (lane & 15)];
          cw[t] = rows[(i + t) * 16 + w0];
        }
#pragma unroll
        for (int t = 0; t < 4; ++t) {
          const int bi = (i + t) & 63;
          const uint64_t keepm = ((cur >> bi) & 1ull) ? 0ull : ~0ull;
          cur |= cw[t] & keepm;
          remv |= rl[t] & keepm;
          kw |= (lane == w0) ? ((1ull << bi) & keepm) : 0ull;
        }
      }
      for (; i < ie; ++i) {                 // scalar tail (fallback NV not /4)
        const int bi = i & 63;
        uint64_t rl = rows[i * 16 + (lane & 15)];
        uint64_t cw = rows[i * 16 + w0];
        const uint64_t keepm = ((cur >> bi) & 1ull) ? 0ull : ~0ull;
        cur |= cw & keepm;
        remv |= rl & keepm;
        kw |= (lane == w0) ? ((1ull << bi) & keepm) : 0ull;
      }
    }
    if (lane < 16) keepw[lane] = kw;
  }
  __syncthreads();
  if (threadIdx.x == 0) {
    uint32_t a = 0;
    for (int w = 0; w < 16; ++w) { pref[w] = a; a += (uint32_t)__popcll((unsigned long long)keepw[w]); }
    pref[16] = a;
  }
  __syncthreads();
  const uint32_t total = pref[16];
  const uint32_t num = total < (uint32_t)KEEP ? total : (uint32_t)KEEP;
  float* o_num = out;
  float* o_box = out + NIMG;
  float* o_s   = out + NIMG + NIMG * KEEP * 4;
  float* o_l   = o_s + NIMG * KEEP;
  if (threadIdx.x == 0) o_num[b] = (float)num;
  const int zstart = NV < KEEP ? NV : KEEP;
  for (int sidx = zstart + threadIdx.x; sidx < KEEP; sidx += 256) {
    ((float4*)o_box)[b * KEEP + sidx] = make_float4(0, 0, 0, 0);
    o_s[b * KEEP + sidx] = 0.0f;
    o_l[b * KEEP + sidx] = 0.0f;
  }
  for (int j = threadIdx.x; j < NV; j += 256) {
    const int wi = j >> 6, bi = j & 63;
    const uint64_t kword = keepw[wi];
    const int isk = (int)((kword >> bi) & 1ull);
    const uint32_t below = pref[wi] + (uint32_t)__popcll((unsigned long long)(kword & ((1ull << bi) - 1ull)));
    const uint32_t slot = isk ? below : (total + (uint32_t)j - below);
    if (slot < (uint32_t)KEEP) {
      ((float4*)o_box)[b * KEEP + slot] = *(const float4*)(topBox + ((size_t)b * PRE + j) * 4);
      o_s[b * KEEP + slot] = isk ? topS[(size_t)b * PRE + j] : 0.0f;
      o_l[b * KEEP + slot] = (float)topLab[(size_t)b * PRE + j];
    }
  }
}

extern "C" void kernel_launch(void* const* d_in, const int* in_sizes, int n_in,
                              void* d_out, int out_size, void* d_ws, size_t ws_size,
                              hipStream_t stream) {
  (void)in_sizes; (void)n_in; (void)out_size; (void)ws_size;
  const float* cls0 = (const float*)d_in[0];
  const float* cls1 = (const float*)d_in[1];
  const float* cls2 = (const float*)d_in[2];
  const float* bbox0 = (const float*)d_in[3];
  const float* bbox1 = (const float*)d_in[4];
  const float* bbox2 = (const float*)d_in[5];
  const float* obj0 = (const float*)d_in[6];
  const float* obj1 = (const float*)d_in[7];
  const float* obj2 = (const float*)d_in[8];
  const float* priors = (const float*)d_in[9];
  const float* strides = (const float*)d_in[10];
  float* out = (float*)d_out;

  char* ws = (char*)d_ws;
  size_t off = 0;
  auto alloc = [&](size_t bytes) -> void* {
    void* p = ws + off;
    off = (off + bytes + 255) & ~(size_t)255;
    return p;
  };
  uint32_t* small       = (uint32_t*)alloc(4096);
  uint32_t* flags       = small;                 // [32]
  uint32_t* cnt75       = small + 32;            // [256]
  uint32_t* candCount   = small + 288;           // [32]
  uint32_t* cutoff      = small + 320;           // [32]
  uint32_t* nvArr       = small + 352;           // [32]
  uint32_t* histDone    = small + 384;           // [32]
  uint32_t* collectDone = small + 416;           // [32]
  uint64_t* cand75    = (uint64_t*)alloc((size_t)NIMG * SUBS * SUBCAP * 8); // 4 MB
  uint32_t* hist      = (uint32_t*)alloc((size_t)NIMG * NBINS * 4);         // 2 MB (fb)
  uint64_t* cand      = (uint64_t*)alloc((size_t)NIMG * CAP * 8);           // 1 MB (fb)
  float*    topS      = (float*)alloc((size_t)NIMG * PRE * 4);
  int*      topLab    = (int*)alloc((size_t)NIMG * PRE * 4);
  float*    topBox    = (float*)alloc((size_t)NIMG * PRE * 16);
  uint64_t* maskbuf   = (uint64_t*)alloc((size_t)NIMG * PRE * 16 * 8);      // 4 MB

  hipError_t _e = hipMemsetAsync(small, 0, 4096, stream); (void)_e;

  k_pass1<<<dim3(54, NIMG), 256, 0, stream>>>(cls0, cls1, cls2, obj0, obj1, obj2,
                                              cnt75, cand75);
  k_gather<<<NIMG, 1024, 0, stream>>>(cand75, cnt75, flags, hist, bbox0, bbox1, bbox2,
                                      priors, strides, topS, topLab, topBox, nvArr);
  dim3 gScan(9, NIMG);
  k_hist_fb<<<gScan, 256, 0, stream>>>(cls0, cls1, cls2, obj0, obj1, obj2, hist, flags,
                                       histDone, cutoff);
  k_collect_fb<<<gScan, 256, 0, stream>>>(cls0, cls1, cls2, obj0, obj1, obj2,
                                          cutoff, candCount, cand, flags, collectDone,
                                          bbox0, bbox1, bbox2, priors, strides,
                                          topS, topLab, topBox, nvArr);
  k_iou<<<dim3(63, NIMG), 256, 0, stream>>>(topBox, topLab, nvArr, maskbuf);
  k_scan_out<<<NIMG, 256, 0, stream>>>(maskbuf, topS, topLab, topBox, nvArr, out);
}